// Round 8
// baseline (411.502 us; speedup 1.0000x reference)
//
#include <hip/hip_runtime.h>
#include <hip/hip_bf16.h>

#define NNODES 50000
#define NEDGES 500000
#define INCH 128
#define HID 64
#define HEADS 4
#define FDIM 256
#define NGRAPHS 64
#define OUTCH 16
#define NEG_SLOPE 0.2f

#define BM 64
#define BN 256
#define BK 32

typedef float f32x4 __attribute__((ext_vector_type(4)));
typedef _Float16 f16x8 __attribute__((ext_vector_type(8)));
typedef _Float16 f16x4 __attribute__((ext_vector_type(4)));

__device__ inline void gld_lds16(const void* g, void* l) {
    __builtin_amdgcn_global_load_lds((__attribute__((address_space(1))) void*)g,
                                     (__attribute__((address_space(3))) void*)l, 16, 0, 0);
}

// ---------------- CSR build ----------------

__global__ void k_hist(const int* __restrict__ dst, int E, int* __restrict__ counts) {
    int i = blockIdx.x * blockDim.x + threadIdx.x;
    if (i < E) atomicAdd(&counts[dst[i]], 1);
}

__global__ __launch_bounds__(256) void k_blocksum(const int* __restrict__ counts, int N,
                                                  int* __restrict__ bsum) {
    int idx = blockIdx.x * 256 + threadIdx.x;
    int v = (idx < N) ? counts[idx] : 0;
#pragma unroll
    for (int off = 32; off; off >>= 1) v += __shfl_xor(v, off);
    __shared__ int wsum[4];
    if ((threadIdx.x & 63) == 0) wsum[threadIdx.x >> 6] = v;
    __syncthreads();
    if (threadIdx.x == 0) bsum[blockIdx.x] = wsum[0] + wsum[1] + wsum[2] + wsum[3];
}

__global__ __launch_bounds__(256) void k_scanfinal(const int* __restrict__ counts,
                                                   const int* __restrict__ bsum, int N,
                                                   int* __restrict__ rowstart,
                                                   int* __restrict__ cursor) {
    __shared__ int tmp[256];
    __shared__ int wsum[4];
    int t = threadIdx.x, b = blockIdx.x;
    int p = 0;
    for (int i = t; i < b; i += 256) p += bsum[i];
#pragma unroll
    for (int off = 32; off; off >>= 1) p += __shfl_xor(p, off);
    int idx = b * 256 + t;
    int v = (idx < N) ? counts[idx] : 0;
    tmp[t] = v;
    if ((t & 63) == 0) wsum[t >> 6] = p;
    __syncthreads();
    int bp = wsum[0] + wsum[1] + wsum[2] + wsum[3];
    for (int off = 1; off < 256; off <<= 1) {
        int u = (t >= off) ? tmp[t - off] : 0;
        __syncthreads();
        tmp[t] += u;
        __syncthreads();
    }
    if (idx < N) {
        int incl = bp + tmp[t];
        rowstart[idx + 1] = incl;
        cursor[idx] = incl - v;
    }
    if (idx == 0) rowstart[0] = 0;
}

__global__ void k_scatter(const int* __restrict__ src, const int* __restrict__ dst, int E,
                          int* __restrict__ cursor, int* __restrict__ csr_src) {
    int i = blockIdx.x * blockDim.x + threadIdx.x;
    if (i < E) {
        int p = atomicAdd(&cursor[dst[i]], 1);
        csr_src[p] = src[i];
    }
}

// ---------------- weight transpose to f16: W[K][256] -> Wt[256][K] ----------------

__global__ void k_wdecomp(const float* __restrict__ W, _Float16* __restrict__ Wt, int K) {
    int i = blockIdx.x * 256 + threadIdx.x;
    if (i >= K * 256) return;
    int k = i >> 8, n = i & 255;
    Wt[n * K + k] = (_Float16)W[i];
}

// ---------------- x -> f16 plane ----------------

__global__ void k_adecomp(const float* __restrict__ X, _Float16* __restrict__ Xf, int total4) {
    int i = blockIdx.x * 256 + threadIdx.x;
    if (i >= total4) return;
    float4 v = ((const float4*)X)[i];
    f16x4 o = {(_Float16)v.x, (_Float16)v.y, (_Float16)v.z, (_Float16)v.w};
    ((f16x4*)Xf)[i] = o;
}

// ---------------- f16 MFMA GEMM, BM=64, double-buffered gld_lds; LDS epilogue ----------------
// K-loop LDS: linear [rows][BK], 16B-chunk swizzle sc = lc ^ ((row>>1)&3) on the global
// source address (gld_lds writes linearly) and on the ds_read chunk index.
// Epilogue: acc -> Hs (64x256 f16 in LDS, chunk swizz cc^(row&7)) -> (a) flat coalesced
// dwordx4 H stores, (b) per-(row,head) score dots (no shuffles: one head == one thread chunk).

__global__ __launch_bounds__(256) void k_gemm_mfma(
    const _Float16* __restrict__ A, const _Float16* __restrict__ B,
    const float* __restrict__ av, const float* __restrict__ dv,
    _Float16* __restrict__ Hf,
    float* __restrict__ ssrcO, float* __restrict__ sdstO, int M, int K) {
    __shared__ _Float16 sA[2][BM * BK];   // 2 x 4 KB
    __shared__ _Float16 sB[2][BN * BK];   // 2 x 16 KB

    const int t = threadIdx.x;
    const int row0 = blockIdx.x * BM;
    const int wv = t >> 6, ln = t & 63, lr = ln & 15, lk = ln >> 4;

    const int ar = wv * 16 + (ln >> 2);              // staged row
    const int alc = (ln & 3) ^ ((ar >> 1) & 3);      // logical 16B chunk to fetch
    const size_t agoff = (size_t)min(row0 + ar, M - 1) * K + alc * 8;
    const int fsc = lk ^ ((lr >> 1) & 3);            // fragment-read stored chunk

    f32x4 acc[4][4] = {};
    const int nt = K / BK;

#define STAGE(tt, p)                                                        \
    do {                                                                    \
        int _k0 = (tt)*BK;                                                  \
        gld_lds16(A + agoff + _k0, &sA[p][wv * 512]);                       \
        _Pragma("unroll") for (int _j = 0; _j < 4; ++_j) {                  \
            int _br = _j * 64 + ar;                                         \
            gld_lds16(B + (size_t)_br * K + _k0 + alc * 8,                  \
                      &sB[p][_j * 2048 + wv * 512]);                        \
        }                                                                   \
    } while (0)

    STAGE(0, 0);
    __syncthreads();
    for (int tt = 0; tt < nt; ++tt) {
        int cur = tt & 1;
        if (tt + 1 < nt) STAGE(tt + 1, cur ^ 1);  // in flight during compute

        f16x8 af[4];
#pragma unroll
        for (int mi = 0; mi < 4; ++mi)
            af[mi] = *(const f16x8*)&sA[cur][(mi * 16 + lr) * BK + fsc * 8];
#pragma unroll
        for (int ni = 0; ni < 4; ++ni) {
            f16x8 bf = *(const f16x8*)&sB[cur][(wv * 64 + ni * 16 + lr) * BK + fsc * 8];
#pragma unroll
            for (int mi = 0; mi < 4; ++mi)
                acc[mi][ni] = __builtin_amdgcn_mfma_f32_16x16x32_f16(af[mi], bf, acc[mi][ni], 0, 0, 0);
        }
        __syncthreads();
    }
#undef STAGE

    // ---- epilogue phase 1: acc -> Hs (swizzled 64x256 f16 in sB; safe after last barrier) ----
    _Float16* Hs = (_Float16*)sB;
#pragma unroll
    for (int mi = 0; mi < 4; ++mi) {
#pragma unroll
        for (int ni = 0; ni < 4; ++ni) {
            int col = wv * 64 + ni * 16 + lr;
            int cc = col >> 3;
#pragma unroll
            for (int j = 0; j < 4; ++j) {
                int row = mi * 16 + lk * 4 + j;
                Hs[row * 256 + ((cc ^ (row & 7)) << 3) + (col & 7)] = (_Float16)acc[mi][ni][j];
            }
        }
    }
    __syncthreads();

    // ---- phase 2: coalesced H store (flat 16B chunks; 1KB contiguous per wave-instr) ----
#pragma unroll
    for (int i = 0; i < 8; ++i) {
        int f = i * 256 + t;
        int row = f >> 5, ccl = f & 31;
        if (row0 + row < M)
            *(f16x8*)(Hf + (size_t)(row0 + row) * FDIM + ccl * 8) =
                *(const f16x8*)&Hs[row * 256 + ((ccl ^ (row & 7)) << 3)];
    }

    // ---- phase 3: scores; thread t -> row t>>2, head t&3 (64 cols = full head, no shfl) ----
    {
        int srow = t >> 2, head = t & 3;
        if (row0 + srow < M) {
            float s = 0.f, q = 0.f;
#pragma unroll
            for (int j = 0; j < 8; ++j) {
                f16x8 hv = *(const f16x8*)&Hs[srow * 256 + (((head * 8 + j) ^ (srow & 7)) << 3)];
#pragma unroll
                for (int e = 0; e < 8; ++e) {
                    float x = (float)hv[e];
                    s += x * av[head * 64 + j * 8 + e];
                    q += x * dv[head * 64 + j * 8 + e];
                }
            }
            ssrcO[(row0 + srow) * HEADS + head] = s;
            sdstO[(row0 + srow) * HEADS + head] = q;
        }
    }
}

// ---------------- softmax prep: one thread per node, float4 across heads, 2 passes ----------------
// Stores UNNORMALIZED w per edge (wcsr[r] float4) + per-node self weight and 1/denom.

__global__ __launch_bounds__(256) void k_edgew(
    const float* __restrict__ ssrc, const float* __restrict__ sdst,
    const int* __restrict__ rowstart, const int* __restrict__ csr_src,
    float* __restrict__ wcsr, float* __restrict__ selfw, float* __restrict__ winv, int N) {
    int n = blockIdx.x * 256 + threadIdx.x;
    if (n >= N) return;
    int r0 = rowstart[n], r1 = rowstart[n + 1];
    float4 sd = *(const float4*)&sdst[n * 4];
    float4 es = *(const float4*)&ssrc[n * 4];
    es.x += sd.x; es.y += sd.y; es.z += sd.z; es.w += sd.w;
    es.x = (es.x > 0.f) ? es.x : NEG_SLOPE * es.x;
    es.y = (es.y > 0.f) ? es.y : NEG_SLOPE * es.y;
    es.z = (es.z > 0.f) ? es.z : NEG_SLOPE * es.z;
    es.w = (es.w > 0.f) ? es.w : NEG_SLOPE * es.w;
    float4 m = es;
    for (int r = r0; r < r1; ++r) {
        int s = csr_src[r];
        float4 sc = *(const float4*)&ssrc[s * 4];
        sc.x += sd.x; sc.y += sd.y; sc.z += sd.z; sc.w += sd.w;
        sc.x = (sc.x > 0.f) ? sc.x : NEG_SLOPE * sc.x;
        sc.y = (sc.y > 0.f) ? sc.y : NEG_SLOPE * sc.y;
        sc.z = (sc.z > 0.f) ? sc.z : NEG_SLOPE * sc.z;
        sc.w = (sc.w > 0.f) ? sc.w : NEG_SLOPE * sc.w;
        m.x = fmaxf(m.x, sc.x); m.y = fmaxf(m.y, sc.y);
        m.z = fmaxf(m.z, sc.z); m.w = fmaxf(m.w, sc.w);
    }
    float4 ws;
    ws.x = __expf(es.x - m.x); ws.y = __expf(es.y - m.y);
    ws.z = __expf(es.z - m.z); ws.w = __expf(es.w - m.w);
    float4 den = ws;
    for (int r = r0; r < r1; ++r) {
        int s = csr_src[r];
        float4 sc = *(const float4*)&ssrc[s * 4];
        sc.x += sd.x; sc.y += sd.y; sc.z += sd.z; sc.w += sd.w;
        sc.x = (sc.x > 0.f) ? sc.x : NEG_SLOPE * sc.x;
        sc.y = (sc.y > 0.f) ? sc.y : NEG_SLOPE * sc.y;
        sc.z = (sc.z > 0.f) ? sc.z : NEG_SLOPE * sc.z;
        sc.w = (sc.w > 0.f) ? sc.w : NEG_SLOPE * sc.w;
        float4 w;
        w.x = __expf(sc.x - m.x); w.y = __expf(sc.y - m.y);
        w.z = __expf(sc.z - m.z); w.w = __expf(sc.w - m.w);
        *(float4*)&wcsr[r * 4] = w;
        den.x += w.x; den.y += w.y; den.z += w.z; den.w += w.w;
    }
    *(float4*)&selfw[n * 4] = ws;
    float4 iv = make_float4(1.f / den.x, 1.f / den.y, 1.f / den.z, 1.f / den.w);
    *(float4*)&winv[n * 4] = iv;
}

// ---------------- aggregation: weighted gather-sum; normalization folded in ----------------

__global__ __launch_bounds__(256) void k_aggregate(
    const _Float16* __restrict__ hf,
    const float* __restrict__ wcsr, const float* __restrict__ selfw,
    const float* __restrict__ winv,
    const int* __restrict__ rowstart, const int* __restrict__ csr_src,
    const float* __restrict__ bias,
    _Float16* __restrict__ outf, int N) {
    int wv = threadIdx.x >> 6, ln = threadIdx.x & 63;
    int n = blockIdx.x * 4 + wv;
    if (n >= N) return;
    int head = ln >> 4;
    int fo = head * 64 + (ln & 15) * 4;
    float a0 = selfw[n * 4 + head];
    float inv = winv[n * 4 + head];
    f16x4 sv = *(const f16x4*)&hf[(size_t)n * FDIM + fo];
    float4 acc = make_float4(a0 * (float)sv[0], a0 * (float)sv[1],
                             a0 * (float)sv[2], a0 * (float)sv[3]);
    int r0 = rowstart[n], r1 = rowstart[n + 1];
    int cnt = r1 - r0;
    for (int base = 0; base < cnt; base += 8) {
        int s[8];
        float w[8];
        f16x4 u[8];
#pragma unroll
        for (int i = 0; i < 8; ++i) {
            int rr = min(r0 + base + i, r1 - 1);
            s[i] = csr_src[rr];
            w[i] = wcsr[rr * 4 + head];
        }
#pragma unroll
        for (int i = 0; i < 8; ++i) u[i] = *(const f16x4*)&hf[(size_t)s[i] * FDIM + fo];
#pragma unroll
        for (int i = 0; i < 8; ++i) w[i] = (base + i < cnt) ? w[i] : 0.f;
#pragma unroll
        for (int i = 0; i < 8; ++i) {
            acc.x += w[i] * (float)u[i][0];
            acc.y += w[i] * (float)u[i][1];
            acc.z += w[i] * (float)u[i][2];
            acc.w += w[i] * (float)u[i][3];
        }
    }
    float4 bv = *(const float4*)&bias[fo];
    f16x4 o;
    o[0] = (_Float16)fmaxf(acc.x * inv + bv.x, 0.f);
    o[1] = (_Float16)fmaxf(acc.y * inv + bv.y, 0.f);
    o[2] = (_Float16)fmaxf(acc.z * inv + bv.z, 0.f);
    o[3] = (_Float16)fmaxf(acc.w * inv + bv.w, 0.f);
    *(f16x4*)&outf[(size_t)n * FDIM + fo] = o;
}

// ---------------- pooling (batch sorted, f16 plane) ----------------

__global__ __launch_bounds__(256) void k_pool(const _Float16* __restrict__ hf,
                                              const int* __restrict__ batch,
                                              float* __restrict__ pooled, int N) {
    int f = threadIdx.x;
    int n0 = blockIdx.x * 128;
    if (n0 >= N) return;
    int n1 = min(n0 + 128, N);
    int g = batch[n0];
    float run = 0.f;
    for (int n = n0; n < n1; ++n) {
        int gn = batch[n];
        if (gn != g) {
            atomicAdd(&pooled[g * FDIM + f], run);
            run = 0.f;
            g = gn;
        }
        run += (float)hf[(size_t)n * FDIM + f];
    }
    atomicAdd(&pooled[g * FDIM + f], run);
}

// ---------------- final classifier ----------------

__global__ __launch_bounds__(256) void k_final(const float* __restrict__ pooled,
                                               const float* __restrict__ Wc,
                                               const float* __restrict__ bc,
                                               float* __restrict__ out) {
    int tid = blockIdx.x * 256 + threadIdx.x;
    int g = tid >> 4, o = tid & 15;
    float s = bc[o];
    for (int k = 0; k < FDIM; ++k) s += pooled[g * FDIM + k] * Wc[k * OUTCH + o];
    out[g * OUTCH + o] = s;
}

// ---------------- launch ----------------

extern "C" void kernel_launch(void* const* d_in, const int* in_sizes, int n_in,
                              void* d_out, int out_size, void* d_ws, size_t ws_size,
                              hipStream_t stream) {
    const float* x = (const float*)d_in[0];
    const int* edge_index = (const int*)d_in[2];
    const int* batch = (const int*)d_in[3];
    const float* W[3]    = {(const float*)d_in[4], (const float*)d_in[8],  (const float*)d_in[12]};
    const float* asrc[3] = {(const float*)d_in[5], (const float*)d_in[9],  (const float*)d_in[13]};
    const float* adst[3] = {(const float*)d_in[6], (const float*)d_in[10], (const float*)d_in[14]};
    const float* bias[3] = {(const float*)d_in[7], (const float*)d_in[11], (const float*)d_in[15]};
    const float* Wc = (const float*)d_in[16];
    const float* bc = (const float*)d_in[17];

    const int N = in_sizes[3];
    const int E = in_sizes[2] / 2;
    const int* e_src = edge_index;
    const int* e_dst = edge_index + E;

    char* ws = (char*)d_ws;
    size_t off = 0;
    _Float16* hb = (_Float16*)(ws + off); off += (size_t)N * FDIM * 2;   // 25.6 MB
    _Float16* xf = (_Float16*)(ws + off); off += (size_t)N * INCH * 2;   // 12.8 MB
    _Float16* P  = (_Float16*)(ws + off); off += (size_t)N * FDIM * 2;   // 25.6 MB
    float* ssrc = (float*)(ws + off); off += (size_t)N * HEADS * 4;
    float* sdst = (float*)(ws + off); off += (size_t)N * HEADS * 4;
    float* wcsr = (float*)(ws + off); off += (size_t)E * HEADS * 4;      // 8 MB
    float* selfw = (float*)(ws + off); off += (size_t)N * HEADS * 4;
    float* winv = (float*)(ws + off); off += (size_t)N * HEADS * 4;
    int* rowstart = (int*)(ws + off); off += ((size_t)(N + 1) * 4 + 255) / 256 * 256;
    int* counts = (int*)(ws + off); off += (size_t)N * 4;
    int* cursor = (int*)(ws + off); off += (size_t)N * 4;
    int* csr_src = (int*)(ws + off); off += (size_t)E * 4;
    float* pooled = (float*)(ws + off); off += (size_t)NGRAPHS * FDIM * 4;
    int* bsum = (int*)(ws + off); off += ((size_t)((N + 255) / 256) * 4 + 255) / 256 * 256;
    _Float16* Wt[3];
    int Ks[3] = {INCH, FDIM, FDIM};
    for (int l = 0; l < 3; ++l) {
        Wt[l] = (_Float16*)(ws + off); off += (size_t)256 * Ks[l] * 2;
    }

    const int nb = (N + 255) / 256;

    // ---- CSR build ----
    hipMemsetAsync(counts, 0, (size_t)N * 4, stream);
    k_hist<<<(E + 255) / 256, 256, 0, stream>>>(e_dst, E, counts);
    k_blocksum<<<nb, 256, 0, stream>>>(counts, N, bsum);
    k_scanfinal<<<nb, 256, 0, stream>>>(counts, bsum, N, rowstart, cursor);
    k_scatter<<<(E + 255) / 256, 256, 0, stream>>>(e_src, e_dst, E, cursor, csr_src);

    // ---- input + weight conversion to f16 planes ----
    k_adecomp<<<((N * INCH / 4) + 255) / 256, 256, 0, stream>>>(x, xf, N * INCH / 4);
    for (int l = 0; l < 3; ++l)
        k_wdecomp<<<(Ks[l] * 256 + 255) / 256, 256, 0, stream>>>(W[l], Wt[l], Ks[l]);

    // ---- 3 GAT layers ----
    const _Float16* Af = xf;
    for (int l = 0; l < 3; ++l) {
        int K = Ks[l];
        k_gemm_mfma<<<(N + BM - 1) / BM, 256, 0, stream>>>(Af, Wt[l], asrc[l], adst[l],
                                                           hb, ssrc, sdst, N, K);
        k_edgew<<<(N + 255) / 256, 256, 0, stream>>>(ssrc, sdst, rowstart, csr_src,
                                                     wcsr, selfw, winv, N);
        k_aggregate<<<(N + 3) / 4, 256, 0, stream>>>(hb, wcsr, selfw, winv, rowstart,
                                                     csr_src, bias[l], P, N);
        Af = P;
    }

    // ---- pool + classifier ----
    hipMemsetAsync(pooled, 0, (size_t)NGRAPHS * FDIM * 4, stream);
    k_pool<<<(N + 127) / 128, 256, 0, stream>>>(P, batch, pooled, N);
    k_final<<<4, 256, 0, stream>>>(pooled, Wc, bc, (float*)d_out);
}

// Round 9
// 384.299 us; speedup vs baseline: 1.0708x; 1.0708x over previous
//
#include <hip/hip_runtime.h>
#include <hip/hip_bf16.h>

#define NNODES 50000
#define NEDGES 500000
#define INCH 128
#define HID 64
#define HEADS 4
#define FDIM 256
#define NGRAPHS 64
#define OUTCH 16
#define NEG_SLOPE 0.2f

#define BM 64
#define BN 256
#define BK 32

typedef float f32x4 __attribute__((ext_vector_type(4)));
typedef _Float16 f16x8 __attribute__((ext_vector_type(8)));
typedef _Float16 f16x4 __attribute__((ext_vector_type(4)));

__device__ inline void gld_lds16(const void* g, void* l) {
    __builtin_amdgcn_global_load_lds((__attribute__((address_space(1))) void*)g,
                                     (__attribute__((address_space(3))) void*)l, 16, 0, 0);
}

// ---------------- CSR build ----------------

__global__ void k_hist(const int* __restrict__ dst, int E, int* __restrict__ counts) {
    int i = blockIdx.x * blockDim.x + threadIdx.x;
    if (i < E) atomicAdd(&counts[dst[i]], 1);
}

__global__ __launch_bounds__(256) void k_blocksum(const int* __restrict__ counts, int N,
                                                  int* __restrict__ bsum) {
    int idx = blockIdx.x * 256 + threadIdx.x;
    int v = (idx < N) ? counts[idx] : 0;
#pragma unroll
    for (int off = 32; off; off >>= 1) v += __shfl_xor(v, off);
    __shared__ int wsum[4];
    if ((threadIdx.x & 63) == 0) wsum[threadIdx.x >> 6] = v;
    __syncthreads();
    if (threadIdx.x == 0) bsum[blockIdx.x] = wsum[0] + wsum[1] + wsum[2] + wsum[3];
}

__global__ __launch_bounds__(256) void k_scanfinal(const int* __restrict__ counts,
                                                   const int* __restrict__ bsum, int N,
                                                   int* __restrict__ rowstart,
                                                   int* __restrict__ cursor) {
    __shared__ int tmp[256];
    __shared__ int wsum[4];
    int t = threadIdx.x, b = blockIdx.x;
    int p = 0;
    for (int i = t; i < b; i += 256) p += bsum[i];
#pragma unroll
    for (int off = 32; off; off >>= 1) p += __shfl_xor(p, off);
    int idx = b * 256 + t;
    int v = (idx < N) ? counts[idx] : 0;
    tmp[t] = v;
    if ((t & 63) == 0) wsum[t >> 6] = p;
    __syncthreads();
    int bp = wsum[0] + wsum[1] + wsum[2] + wsum[3];
    for (int off = 1; off < 256; off <<= 1) {
        int u = (t >= off) ? tmp[t - off] : 0;
        __syncthreads();
        tmp[t] += u;
        __syncthreads();
    }
    if (idx < N) {
        int incl = bp + tmp[t];
        rowstart[idx + 1] = incl;
        cursor[idx] = incl - v;
    }
    if (idx == 0) rowstart[0] = 0;
}

__global__ void k_scatter(const int* __restrict__ src, const int* __restrict__ dst, int E,
                          int* __restrict__ cursor, int* __restrict__ csr_src) {
    int i = blockIdx.x * blockDim.x + threadIdx.x;
    if (i < E) {
        int p = atomicAdd(&cursor[dst[i]], 1);
        csr_src[p] = src[i];
    }
}

// ---------------- fused conversion: x -> f16 plane, W[l] -> transposed f16 ----------------
// block ranges: [0,bx): x float4 copy; then 128/256/256 blocks for W0/W1/W2 transpose.

__device__ inline void wdecomp_body(const float* __restrict__ W, _Float16* __restrict__ Wt,
                                    int K, int bb) {
    int i = bb * 256 + threadIdx.x;      // grid sized exactly K*256/256 blocks
    int k = i >> 8, n = i & 255;
    Wt[n * K + k] = (_Float16)W[i];
}

__global__ __launch_bounds__(256) void k_convert(
    const float* __restrict__ X, _Float16* __restrict__ Xf, int bx,
    const float* __restrict__ W0, _Float16* __restrict__ Wt0,
    const float* __restrict__ W1, _Float16* __restrict__ Wt1,
    const float* __restrict__ W2, _Float16* __restrict__ Wt2) {
    int b = blockIdx.x;
    if (b < bx) {
        int i = b * 256 + threadIdx.x;
        float4 v = ((const float4*)X)[i];
        f16x4 o = {(_Float16)v.x, (_Float16)v.y, (_Float16)v.z, (_Float16)v.w};
        ((f16x4*)Xf)[i] = o;
    } else if (b < bx + 128) {
        wdecomp_body(W0, Wt0, INCH, b - bx);
    } else if (b < bx + 384) {
        wdecomp_body(W1, Wt1, FDIM, b - bx - 128);
    } else {
        wdecomp_body(W2, Wt2, FDIM, b - bx - 384);
    }
}

// ---------------- f16 MFMA GEMM, BM=64, double-buffered gld_lds, fused scores ----------------
// (round-6 measured-good version, unchanged)

__global__ __launch_bounds__(256) void k_gemm_mfma(
    const _Float16* __restrict__ A, const _Float16* __restrict__ B,
    const float* __restrict__ av, const float* __restrict__ dv,
    _Float16* __restrict__ Hf,
    float* __restrict__ ssrcO, float* __restrict__ sdstO, int M, int K) {
    __shared__ _Float16 sA[2][BM * BK];
    __shared__ _Float16 sB[2][BN * BK];

    const int t = threadIdx.x;
    const int row0 = blockIdx.x * BM;
    const int wv = t >> 6, ln = t & 63, lr = ln & 15, lk = ln >> 4;

    const int ar = wv * 16 + (ln >> 2);
    const int alc = (ln & 3) ^ ((ar >> 1) & 3);
    const size_t agoff = (size_t)min(row0 + ar, M - 1) * K + alc * 8;
    const int fsc = lk ^ ((lr >> 1) & 3);

    f32x4 acc[4][4] = {};
    const int nt = K / BK;

#define STAGE(tt, p)                                                        \
    do {                                                                    \
        int _k0 = (tt)*BK;                                                  \
        gld_lds16(A + agoff + _k0, &sA[p][wv * 512]);                       \
        _Pragma("unroll") for (int _j = 0; _j < 4; ++_j) {                  \
            int _br = _j * 64 + ar;                                         \
            gld_lds16(B + (size_t)_br * K + _k0 + alc * 8,                  \
                      &sB[p][_j * 2048 + wv * 512]);                        \
        }                                                                   \
    } while (0)

    STAGE(0, 0);
    __syncthreads();
    for (int tt = 0; tt < nt; ++tt) {
        int cur = tt & 1;
        if (tt + 1 < nt) STAGE(tt + 1, cur ^ 1);

        f16x8 af[4];
#pragma unroll
        for (int mi = 0; mi < 4; ++mi)
            af[mi] = *(const f16x8*)&sA[cur][(mi * 16 + lr) * BK + fsc * 8];
#pragma unroll
        for (int ni = 0; ni < 4; ++ni) {
            f16x8 bf = *(const f16x8*)&sB[cur][(wv * 64 + ni * 16 + lr) * BK + fsc * 8];
#pragma unroll
            for (int mi = 0; mi < 4; ++mi)
                acc[mi][ni] = __builtin_amdgcn_mfma_f32_16x16x32_f16(af[mi], bf, acc[mi][ni], 0, 0, 0);
        }
        __syncthreads();
    }
#undef STAGE

    float ps[4][4] = {}, pd[4][4] = {};
#pragma unroll
    for (int ni = 0; ni < 4; ++ni) {
        int col = wv * 64 + ni * 16 + lr;
        float a_s = av[col], a_d = dv[col];
#pragma unroll
        for (int mi = 0; mi < 4; ++mi) {
            f32x4 v = acc[mi][ni];
            int r = row0 + mi * 16 + lk * 4;
#pragma unroll
            for (int j = 0; j < 4; ++j) {
                if (r + j < M) Hf[(size_t)(r + j) * FDIM + col] = (_Float16)v[j];
                ps[mi][j] += v[j] * a_s;
                pd[mi][j] += v[j] * a_d;
            }
        }
    }
#pragma unroll
    for (int mi = 0; mi < 4; ++mi) {
#pragma unroll
        for (int j = 0; j < 4; ++j) {
            float s = ps[mi][j], q = pd[mi][j];
            s += __shfl_xor(s, 1); s += __shfl_xor(s, 2);
            s += __shfl_xor(s, 4); s += __shfl_xor(s, 8);
            q += __shfl_xor(q, 1); q += __shfl_xor(q, 2);
            q += __shfl_xor(q, 4); q += __shfl_xor(q, 8);
            if (lr == 0) {
                int r = row0 + mi * 16 + lk * 4 + j;
                if (r < M) {
                    ssrcO[r * HEADS + wv] = s;
                    sdstO[r * HEADS + wv] = q;
                }
            }
        }
    }
}

// ---------------- flash softmax + aggregation: predicated groups of 16 ----------------

__global__ __launch_bounds__(256) void k_aggregate(
    const _Float16* __restrict__ hf,
    const float* __restrict__ ssrc, const float* __restrict__ sdst,
    const int* __restrict__ rowstart, const int* __restrict__ csr_src,
    const float* __restrict__ bias,
    _Float16* __restrict__ outf, int N) {
    int wv = threadIdx.x >> 6, ln = threadIdx.x & 63;
    int n = blockIdx.x * 4 + wv;
    if (n >= N) return;
    int head = ln >> 4;
    int fo = head * 64 + (ln & 15) * 4;
    float sd = sdst[n * HEADS + head];
    float e = ssrc[n * HEADS + head] + sd;
    e = (e > 0.f) ? e : NEG_SLOPE * e;
    float m = e, d = 1.0f;
    f16x4 sv = *(const f16x4*)&hf[(size_t)n * FDIM + fo];
    float4 acc = make_float4((float)sv[0], (float)sv[1], (float)sv[2], (float)sv[3]);
    int r0 = rowstart[n], r1 = rowstart[n + 1];
    int cnt = r1 - r0;
    for (int base = 0; base < cnt; base += 16) {
        int s[16];
        f16x4 u[16];
        float c[16], w[16];
#pragma unroll
        for (int i = 0; i < 16; ++i) s[i] = csr_src[min(r0 + base + i, r1 - 1)];
#pragma unroll
        for (int i = 0; i < 16; ++i) u[i] = *(const f16x4*)&hf[(size_t)s[i] * FDIM + fo];
#pragma unroll
        for (int i = 0; i < 16; ++i) {
            float sc = ssrc[s[i] * HEADS + head] + sd;
            sc = (sc > 0.f) ? sc : NEG_SLOPE * sc;
            c[i] = (base + i < cnt) ? sc : -1e30f;
        }
        float mx = c[0];
#pragma unroll
        for (int i = 1; i < 16; ++i) mx = fmaxf(mx, c[i]);
        float mn = fmaxf(m, mx);
        float wa = __expf(m - mn);
#pragma unroll
        for (int i = 0; i < 16; ++i) w[i] = __expf(c[i] - mn);
        float sx = 0.f, sy = 0.f, sz = 0.f, sw = 0.f, sdn = 0.f;
#pragma unroll
        for (int i = 0; i < 16; ++i) {
            sx += w[i] * (float)u[i][0];
            sy += w[i] * (float)u[i][1];
            sz += w[i] * (float)u[i][2];
            sw += w[i] * (float)u[i][3];
            sdn += w[i];
        }
        acc.x = acc.x * wa + sx;
        acc.y = acc.y * wa + sy;
        acc.z = acc.z * wa + sz;
        acc.w = acc.w * wa + sw;
        d = d * wa + sdn;
        m = mn;
    }
    float inv = 1.0f / d;
    float4 bv = *(const float4*)&bias[fo];
    f16x4 o;
    o[0] = (_Float16)fmaxf(acc.x * inv + bv.x, 0.f);
    o[1] = (_Float16)fmaxf(acc.y * inv + bv.y, 0.f);
    o[2] = (_Float16)fmaxf(acc.z * inv + bv.z, 0.f);
    o[3] = (_Float16)fmaxf(acc.w * inv + bv.w, 0.f);
    *(f16x4*)&outf[(size_t)n * FDIM + fo] = o;
}

// ---------------- pooling (batch sorted, f16 plane) ----------------

__global__ __launch_bounds__(256) void k_pool(const _Float16* __restrict__ hf,
                                              const int* __restrict__ batch,
                                              float* __restrict__ pooled, int N) {
    int f = threadIdx.x;
    int n0 = blockIdx.x * 128;
    if (n0 >= N) return;
    int n1 = min(n0 + 128, N);
    int g = batch[n0];
    float run = 0.f;
    for (int n = n0; n < n1; ++n) {
        int gn = batch[n];
        if (gn != g) {
            atomicAdd(&pooled[g * FDIM + f], run);
            run = 0.f;
            g = gn;
        }
        run += (float)hf[(size_t)n * FDIM + f];
    }
    atomicAdd(&pooled[g * FDIM + f], run);
}

// ---------------- final classifier ----------------

__global__ __launch_bounds__(256) void k_final(const float* __restrict__ pooled,
                                               const float* __restrict__ Wc,
                                               const float* __restrict__ bc,
                                               float* __restrict__ out) {
    int tid = blockIdx.x * 256 + threadIdx.x;
    int g = tid >> 4, o = tid & 15;
    float s = bc[o];
    for (int k = 0; k < FDIM; ++k) s += pooled[g * FDIM + k] * Wc[k * OUTCH + o];
    out[g * OUTCH + o] = s;
}

// ---------------- launch ----------------

extern "C" void kernel_launch(void* const* d_in, const int* in_sizes, int n_in,
                              void* d_out, int out_size, void* d_ws, size_t ws_size,
                              hipStream_t stream) {
    const float* x = (const float*)d_in[0];
    const int* edge_index = (const int*)d_in[2];
    const int* batch = (const int*)d_in[3];
    const float* W[3]    = {(const float*)d_in[4], (const float*)d_in[8],  (const float*)d_in[12]};
    const float* asrc[3] = {(const float*)d_in[5], (const float*)d_in[9],  (const float*)d_in[13]};
    const float* adst[3] = {(const float*)d_in[6], (const float*)d_in[10], (const float*)d_in[14]};
    const float* bias[3] = {(const float*)d_in[7], (const float*)d_in[11], (const float*)d_in[15]};
    const float* Wc = (const float*)d_in[16];
    const float* bc = (const float*)d_in[17];

    const int N = in_sizes[3];
    const int E = in_sizes[2] / 2;
    const int* e_src = edge_index;
    const int* e_dst = edge_index + E;

    char* ws = (char*)d_ws;
    size_t off = 0;
    _Float16* hb = (_Float16*)(ws + off); off += (size_t)N * FDIM * 2;   // 25.6 MB
    _Float16* xf = (_Float16*)(ws + off); off += (size_t)N * INCH * 2;   // 12.8 MB
    _Float16* P  = (_Float16*)(ws + off); off += (size_t)N * FDIM * 2;   // 25.6 MB
    float* ssrc = (float*)(ws + off); off += (size_t)N * HEADS * 4;
    float* sdst = (float*)(ws + off); off += (size_t)N * HEADS * 4;
    int* rowstart = (int*)(ws + off); off += ((size_t)(N + 1) * 4 + 255) / 256 * 256;
    int* counts = (int*)(ws + off); off += (size_t)N * 4;
    int* cursor = (int*)(ws + off); off += (size_t)N * 4;
    int* csr_src = (int*)(ws + off); off += (size_t)E * 4;
    float* pooled = (float*)(ws + off); off += (size_t)NGRAPHS * FDIM * 4;
    int* bsum = (int*)(ws + off); off += ((size_t)((N + 255) / 256) * 4 + 255) / 256 * 256;
    _Float16* Wt[3];
    int Ks[3] = {INCH, FDIM, FDIM};
    for (int l = 0; l < 3; ++l) {
        Wt[l] = (_Float16*)(ws + off); off += (size_t)256 * Ks[l] * 2;
    }

    const int nb = (N + 255) / 256;

    // ---- CSR build ----
    hipMemsetAsync(counts, 0, (size_t)N * 4, stream);
    k_hist<<<(E + 255) / 256, 256, 0, stream>>>(e_dst, E, counts);
    k_blocksum<<<nb, 256, 0, stream>>>(counts, N, bsum);
    k_scanfinal<<<nb, 256, 0, stream>>>(counts, bsum, N, rowstart, cursor);
    k_scatter<<<(E + 255) / 256, 256, 0, stream>>>(e_src, e_dst, E, cursor, csr_src);

    // ---- fused input + weight conversion (1 launch) ----
    {
        int bx = (N * INCH / 4) / 256;                      // 6250 for N=50000
        int btot = bx + (Ks[0] * 256) / 256 + (Ks[1] * 256) / 256 + (Ks[2] * 256) / 256;
        k_convert<<<btot, 256, 0, stream>>>(x, xf, bx, W[0], Wt[0], W[1], Wt[1], W[2], Wt[2]);
    }

    // ---- 3 GAT layers ----
    const _Float16* Af = xf;
    for (int l = 0; l < 3; ++l) {
        int K = Ks[l];
        k_gemm_mfma<<<(N + BM - 1) / BM, 256, 0, stream>>>(Af, Wt[l], asrc[l], adst[l],
                                                           hb, ssrc, sdst, N, K);
        k_aggregate<<<(N + 3) / 4, 256, 0, stream>>>(hb, ssrc, sdst, rowstart, csr_src,
                                                     bias[l], P, N);
        Af = P;
    }

    // ---- pool + classifier ----
    hipMemsetAsync(pooled, 0, (size_t)NGRAPHS * FDIM * 4, stream);
    k_pool<<<(N + 127) / 128, 256, 0, stream>>>(P, batch, pooled, N);
    k_final<<<4, 256, 0, stream>>>(pooled, Wc, bc, (float*)d_out);
}

// Round 10
// 358.981 us; speedup vs baseline: 1.1463x; 1.0705x over previous
//
#include <hip/hip_runtime.h>
#include <hip/hip_bf16.h>

#define NNODES 50000
#define NEDGES 500000
#define INCH 128
#define HID 64
#define HEADS 4
#define FDIM 256
#define NGRAPHS 64
#define OUTCH 16
#define NEG_SLOPE 0.2f

#define BM 64
#define BN 256
#define BK 32

typedef float f32x4 __attribute__((ext_vector_type(4)));
typedef _Float16 f16x8 __attribute__((ext_vector_type(8)));
typedef _Float16 f16x4 __attribute__((ext_vector_type(4)));

__device__ inline void gld_lds16(const void* g, void* l) {
    __builtin_amdgcn_global_load_lds((__attribute__((address_space(1))) void*)g,
                                     (__attribute__((address_space(3))) void*)l, 16, 0, 0);
}

// ---------------- CSR build ----------------

__global__ void k_hist(const int* __restrict__ dst, int E, int* __restrict__ counts) {
    int i = blockIdx.x * blockDim.x + threadIdx.x;
    if (i < E) atomicAdd(&counts[dst[i]], 1);
}

__global__ __launch_bounds__(256) void k_blocksum(const int* __restrict__ counts, int N,
                                                  int* __restrict__ bsum) {
    int idx = blockIdx.x * 256 + threadIdx.x;
    int v = (idx < N) ? counts[idx] : 0;
#pragma unroll
    for (int off = 32; off; off >>= 1) v += __shfl_xor(v, off);
    __shared__ int wsum[4];
    if ((threadIdx.x & 63) == 0) wsum[threadIdx.x >> 6] = v;
    __syncthreads();
    if (threadIdx.x == 0) bsum[blockIdx.x] = wsum[0] + wsum[1] + wsum[2] + wsum[3];
}

__global__ __launch_bounds__(256) void k_scanfinal(const int* __restrict__ counts,
                                                   const int* __restrict__ bsum, int N,
                                                   int* __restrict__ rowstart,
                                                   int* __restrict__ cursor) {
    __shared__ int tmp[256];
    __shared__ int wsum[4];
    int t = threadIdx.x, b = blockIdx.x;
    int p = 0;
    for (int i = t; i < b; i += 256) p += bsum[i];
#pragma unroll
    for (int off = 32; off; off >>= 1) p += __shfl_xor(p, off);
    int idx = b * 256 + t;
    int v = (idx < N) ? counts[idx] : 0;
    tmp[t] = v;
    if ((t & 63) == 0) wsum[t >> 6] = p;
    __syncthreads();
    int bp = wsum[0] + wsum[1] + wsum[2] + wsum[3];
    for (int off = 1; off < 256; off <<= 1) {
        int u = (t >= off) ? tmp[t - off] : 0;
        __syncthreads();
        tmp[t] += u;
        __syncthreads();
    }
    if (idx < N) {
        int incl = bp + tmp[t];
        rowstart[idx + 1] = incl;
        cursor[idx] = incl - v;
    }
    if (idx == 0) rowstart[0] = 0;
}

__global__ void k_scatter(const int* __restrict__ src, const int* __restrict__ dst, int E,
                          int* __restrict__ cursor, int* __restrict__ csr_src) {
    int i = blockIdx.x * blockDim.x + threadIdx.x;
    if (i < E) {
        int p = atomicAdd(&cursor[dst[i]], 1);
        csr_src[p] = src[i];
    }
}

// ---------------- fused conversion: x -> f16 plane, W[l] -> transposed f16 ----------------

__device__ inline void wdecomp_body(const float* __restrict__ W, _Float16* __restrict__ Wt,
                                    int K, int bb) {
    int i = bb * 256 + threadIdx.x;
    int k = i >> 8, n = i & 255;
    Wt[n * K + k] = (_Float16)W[i];
}

__global__ __launch_bounds__(256) void k_convert(
    const float* __restrict__ X, _Float16* __restrict__ Xf, int bx,
    const float* __restrict__ W0, _Float16* __restrict__ Wt0,
    const float* __restrict__ W1, _Float16* __restrict__ Wt1,
    const float* __restrict__ W2, _Float16* __restrict__ Wt2) {
    int b = blockIdx.x;
    if (b < bx) {
        int i = b * 256 + threadIdx.x;
        float4 v = ((const float4*)X)[i];
        f16x4 o = {(_Float16)v.x, (_Float16)v.y, (_Float16)v.z, (_Float16)v.w};
        ((f16x4*)Xf)[i] = o;
    } else if (b < bx + 128) {
        wdecomp_body(W0, Wt0, INCH, b - bx);
    } else if (b < bx + 384) {
        wdecomp_body(W1, Wt1, FDIM, b - bx - 128);
    } else {
        wdecomp_body(W2, Wt2, FDIM, b - bx - 384);
    }
}

// ---------------- f16 MFMA GEMM, BM=64, double-buffered gld_lds, fused scores ----------------
// (round-6 measured-good version, unchanged)

__global__ __launch_bounds__(256) void k_gemm_mfma(
    const _Float16* __restrict__ A, const _Float16* __restrict__ B,
    const float* __restrict__ av, const float* __restrict__ dv,
    _Float16* __restrict__ Hf,
    float* __restrict__ ssrcO, float* __restrict__ sdstO, int M, int K) {
    __shared__ _Float16 sA[2][BM * BK];
    __shared__ _Float16 sB[2][BN * BK];

    const int t = threadIdx.x;
    const int row0 = blockIdx.x * BM;
    const int wv = t >> 6, ln = t & 63, lr = ln & 15, lk = ln >> 4;

    const int ar = wv * 16 + (ln >> 2);
    const int alc = (ln & 3) ^ ((ar >> 1) & 3);
    const size_t agoff = (size_t)min(row0 + ar, M - 1) * K + alc * 8;
    const int fsc = lk ^ ((lr >> 1) & 3);

    f32x4 acc[4][4] = {};
    const int nt = K / BK;

#define STAGE(tt, p)                                                        \
    do {                                                                    \
        int _k0 = (tt)*BK;                                                  \
        gld_lds16(A + agoff + _k0, &sA[p][wv * 512]);                       \
        _Pragma("unroll") for (int _j = 0; _j < 4; ++_j) {                  \
            int _br = _j * 64 + ar;                                         \
            gld_lds16(B + (size_t)_br * K + _k0 + alc * 8,                  \
                      &sB[p][_j * 2048 + wv * 512]);                        \
        }                                                                   \
    } while (0)

    STAGE(0, 0);
    __syncthreads();
    for (int tt = 0; tt < nt; ++tt) {
        int cur = tt & 1;
        if (tt + 1 < nt) STAGE(tt + 1, cur ^ 1);

        f16x8 af[4];
#pragma unroll
        for (int mi = 0; mi < 4; ++mi)
            af[mi] = *(const f16x8*)&sA[cur][(mi * 16 + lr) * BK + fsc * 8];
#pragma unroll
        for (int ni = 0; ni < 4; ++ni) {
            f16x8 bf = *(const f16x8*)&sB[cur][(wv * 64 + ni * 16 + lr) * BK + fsc * 8];
#pragma unroll
            for (int mi = 0; mi < 4; ++mi)
                acc[mi][ni] = __builtin_amdgcn_mfma_f32_16x16x32_f16(af[mi], bf, acc[mi][ni], 0, 0, 0);
        }
        __syncthreads();
    }
#undef STAGE

    float ps[4][4] = {}, pd[4][4] = {};
#pragma unroll
    for (int ni = 0; ni < 4; ++ni) {
        int col = wv * 64 + ni * 16 + lr;
        float a_s = av[col], a_d = dv[col];
#pragma unroll
        for (int mi = 0; mi < 4; ++mi) {
            f32x4 v = acc[mi][ni];
            int r = row0 + mi * 16 + lk * 4;
#pragma unroll
            for (int j = 0; j < 4; ++j) {
                if (r + j < M) Hf[(size_t)(r + j) * FDIM + col] = (_Float16)v[j];
                ps[mi][j] += v[j] * a_s;
                pd[mi][j] += v[j] * a_d;
            }
        }
    }
#pragma unroll
    for (int mi = 0; mi < 4; ++mi) {
#pragma unroll
        for (int j = 0; j < 4; ++j) {
            float s = ps[mi][j], q = pd[mi][j];
            s += __shfl_xor(s, 1); s += __shfl_xor(s, 2);
            s += __shfl_xor(s, 4); s += __shfl_xor(s, 8);
            q += __shfl_xor(q, 1); q += __shfl_xor(q, 2);
            q += __shfl_xor(q, 4); q += __shfl_xor(q, 8);
            if (lr == 0) {
                int r = row0 + mi * 16 + lk * 4 + j;
                if (r < M) {
                    ssrcO[r * HEADS + wv] = s;
                    sdstO[r * HEADS + wv] = q;
                }
            }
        }
    }
}

// ---------------- flash softmax + aggregation: cooperative scores, group=8 ----------------
// One wave per node (grid-stride). 16 lanes per head. Per 8-edge group: lanes li<8 compute
// the score for edge li ONCE (vs 16x redundant), group max/sum via shfl_xor (stays inside
// the 16-lane head group since offsets<16), weights broadcast via shfl into the FMA loop.

__global__ __launch_bounds__(256) void k_aggregate(
    const _Float16* __restrict__ hf,
    const float* __restrict__ ssrc, const float* __restrict__ sdst,
    const int* __restrict__ rowstart, const int* __restrict__ csr_src,
    const float* __restrict__ bias,
    _Float16* __restrict__ outf, int N, int nwaves) {
    int wid = (blockIdx.x * blockDim.x + threadIdx.x) >> 6;
    int ln = threadIdx.x & 63;
    int head = ln >> 4, li = ln & 15;
    int fo = head * 64 + li * 4;
    float4 bv = *(const float4*)&bias[fo];

    for (int n = wid; n < N; n += nwaves) {
        float sd = sdst[n * HEADS + head];
        float e = ssrc[n * HEADS + head] + sd;
        e = (e > 0.f) ? e : NEG_SLOPE * e;
        float m = e, d = 1.0f;
        f16x4 sv = *(const f16x4*)&hf[(size_t)n * FDIM + fo];
        float4 acc = make_float4((float)sv[0], (float)sv[1], (float)sv[2], (float)sv[3]);
        int r0 = rowstart[n], r1 = rowstart[n + 1];
        for (int base = r0; base < r1; base += 8) {
            int s[8];
#pragma unroll
            for (int i = 0; i < 8; ++i) s[i] = csr_src[min(base + i, r1 - 1)];
            // one score per (edge, head), computed by lane li<8 of each head group
            float sc = -1e30f;
            if (li < 8 && base + li < r1) {
                sc = ssrc[s[li] * HEADS + head] + sd;
                sc = (sc > 0.f) ? sc : NEG_SLOPE * sc;
            }
            float gmax = sc;
#pragma unroll
            for (int off = 1; off < 16; off <<= 1) gmax = fmaxf(gmax, __shfl_xor(gmax, off));
            float mn = fmaxf(m, gmax);
            float wl = __expf(sc - mn);       // 0 for idle/tail lanes
            float wsum = wl;
#pragma unroll
            for (int off = 1; off < 16; off <<= 1) wsum += __shfl_xor(wsum, off);
            f16x4 u[8];
#pragma unroll
            for (int i = 0; i < 8; ++i) u[i] = *(const f16x4*)&hf[(size_t)s[i] * FDIM + fo];
            float wa = __expf(m - mn);
            float sx = 0.f, sy = 0.f, sz = 0.f, sw = 0.f;
#pragma unroll
            for (int i = 0; i < 8; ++i) {
                float wi = __shfl(wl, head * 16 + i);
                sx += wi * (float)u[i][0];
                sy += wi * (float)u[i][1];
                sz += wi * (float)u[i][2];
                sw += wi * (float)u[i][3];
            }
            acc.x = acc.x * wa + sx;
            acc.y = acc.y * wa + sy;
            acc.z = acc.z * wa + sz;
            acc.w = acc.w * wa + sw;
            d = d * wa + wsum;
            m = mn;
        }
        float inv = 1.0f / d;
        f16x4 o;
        o[0] = (_Float16)fmaxf(acc.x * inv + bv.x, 0.f);
        o[1] = (_Float16)fmaxf(acc.y * inv + bv.y, 0.f);
        o[2] = (_Float16)fmaxf(acc.z * inv + bv.z, 0.f);
        o[3] = (_Float16)fmaxf(acc.w * inv + bv.w, 0.f);
        *(f16x4*)&outf[(size_t)n * FDIM + fo] = o;
    }
}

// ---------------- pooling (batch sorted, f16 plane) ----------------

__global__ __launch_bounds__(256) void k_pool(const _Float16* __restrict__ hf,
                                              const int* __restrict__ batch,
                                              float* __restrict__ pooled, int N) {
    int f = threadIdx.x;
    int n0 = blockIdx.x * 128;
    if (n0 >= N) return;
    int n1 = min(n0 + 128, N);
    int g = batch[n0];
    float run = 0.f;
    for (int n = n0; n < n1; ++n) {
        int gn = batch[n];
        if (gn != g) {
            atomicAdd(&pooled[g * FDIM + f], run);
            run = 0.f;
            g = gn;
        }
        run += (float)hf[(size_t)n * FDIM + f];
    }
    atomicAdd(&pooled[g * FDIM + f], run);
}

// ---------------- final classifier ----------------

__global__ __launch_bounds__(256) void k_final(const float* __restrict__ pooled,
                                               const float* __restrict__ Wc,
                                               const float* __restrict__ bc,
                                               float* __restrict__ out) {
    int tid = blockIdx.x * 256 + threadIdx.x;
    int g = tid >> 4, o = tid & 15;
    float s = bc[o];
    for (int k = 0; k < FDIM; ++k) s += pooled[g * FDIM + k] * Wc[k * OUTCH + o];
    out[g * OUTCH + o] = s;
}

// ---------------- launch ----------------

extern "C" void kernel_launch(void* const* d_in, const int* in_sizes, int n_in,
                              void* d_out, int out_size, void* d_ws, size_t ws_size,
                              hipStream_t stream) {
    const float* x = (const float*)d_in[0];
    const int* edge_index = (const int*)d_in[2];
    const int* batch = (const int*)d_in[3];
    const float* W[3]    = {(const float*)d_in[4], (const float*)d_in[8],  (const float*)d_in[12]};
    const float* asrc[3] = {(const float*)d_in[5], (const float*)d_in[9],  (const float*)d_in[13]};
    const float* adst[3] = {(const float*)d_in[6], (const float*)d_in[10], (const float*)d_in[14]};
    const float* bias[3] = {(const float*)d_in[7], (const float*)d_in[11], (const float*)d_in[15]};
    const float* Wc = (const float*)d_in[16];
    const float* bc = (const float*)d_in[17];

    const int N = in_sizes[3];
    const int E = in_sizes[2] / 2;
    const int* e_src = edge_index;
    const int* e_dst = edge_index + E;

    char* ws = (char*)d_ws;
    size_t off = 0;
    _Float16* hb = (_Float16*)(ws + off); off += (size_t)N * FDIM * 2;
    _Float16* xf = (_Float16*)(ws + off); off += (size_t)N * INCH * 2;
    _Float16* P  = (_Float16*)(ws + off); off += (size_t)N * FDIM * 2;
    float* ssrc = (float*)(ws + off); off += (size_t)N * HEADS * 4;
    float* sdst = (float*)(ws + off); off += (size_t)N * HEADS * 4;
    int* rowstart = (int*)(ws + off); off += ((size_t)(N + 1) * 4 + 255) / 256 * 256;
    int* counts = (int*)(ws + off); off += (size_t)N * 4;
    int* cursor = (int*)(ws + off); off += (size_t)N * 4;
    int* csr_src = (int*)(ws + off); off += (size_t)E * 4;
    float* pooled = (float*)(ws + off); off += (size_t)NGRAPHS * FDIM * 4;
    int* bsum = (int*)(ws + off); off += ((size_t)((N + 255) / 256) * 4 + 255) / 256 * 256;
    _Float16* Wt[3];
    int Ks[3] = {INCH, FDIM, FDIM};
    for (int l = 0; l < 3; ++l) {
        Wt[l] = (_Float16*)(ws + off); off += (size_t)256 * Ks[l] * 2;
    }

    const int nb = (N + 255) / 256;

    // ---- CSR build ----
    hipMemsetAsync(counts, 0, (size_t)N * 4, stream);
    k_hist<<<(E + 255) / 256, 256, 0, stream>>>(e_dst, E, counts);
    k_blocksum<<<nb, 256, 0, stream>>>(counts, N, bsum);
    k_scanfinal<<<nb, 256, 0, stream>>>(counts, bsum, N, rowstart, cursor);
    k_scatter<<<(E + 255) / 256, 256, 0, stream>>>(e_src, e_dst, E, cursor, csr_src);

    // ---- fused input + weight conversion (1 launch) ----
    {
        int bx = (N * INCH / 4) / 256;
        int btot = bx + (Ks[0] * 256) / 256 + (Ks[1] * 256) / 256 + (Ks[2] * 256) / 256;
        k_convert<<<btot, 256, 0, stream>>>(x, xf, bx, W[0], Wt[0], W[1], Wt[1], W[2], Wt[2]);
    }

    // ---- 3 GAT layers ----
    const int aggblocks = 2048;
    const int nwaves = aggblocks * 4;
    const _Float16* Af = xf;
    for (int l = 0; l < 3; ++l) {
        int K = Ks[l];
        k_gemm_mfma<<<(N + BM - 1) / BM, 256, 0, stream>>>(Af, Wt[l], asrc[l], adst[l],
                                                           hb, ssrc, sdst, N, K);
        k_aggregate<<<aggblocks, 256, 0, stream>>>(hb, ssrc, sdst, rowstart, csr_src,
                                                   bias[l], P, N, nwaves);
        Af = P;
    }

    // ---- pool + classifier ----
    hipMemsetAsync(pooled, 0, (size_t)NGRAPHS * FDIM * 4, stream);
    k_pool<<<(N + 127) / 128, 256, 0, stream>>>(P, batch, pooled, N);
    k_final<<<4, 256, 0, stream>>>(pooled, Wc, bc, (float*)d_out);
}

// Round 11
// 346.966 us; speedup vs baseline: 1.1860x; 1.0346x over previous
//
#include <hip/hip_runtime.h>
#include <hip/hip_bf16.h>

#define NNODES 50000
#define NEDGES 500000
#define INCH 128
#define HID 64
#define HEADS 4
#define FDIM 256
#define NGRAPHS 64
#define OUTCH 16
#define NEG_SLOPE 0.2f
#define LOG2E 1.44269504089f

#define BM 64
#define BN 256
#define BK 32

typedef float f32x4 __attribute__((ext_vector_type(4)));
typedef _Float16 f16x8 __attribute__((ext_vector_type(8)));
typedef _Float16 f16x4 __attribute__((ext_vector_type(4)));

__device__ inline void gld_lds16(const void* g, void* l) {
    __builtin_amdgcn_global_load_lds((__attribute__((address_space(1))) void*)g,
                                     (__attribute__((address_space(3))) void*)l, 16, 0, 0);
}

// ---------------- CSR build ----------------

__global__ void k_hist(const int* __restrict__ dst, int E, int* __restrict__ counts) {
    int i = blockIdx.x * blockDim.x + threadIdx.x;
    if (i < E) atomicAdd(&counts[dst[i]], 1);
}

__global__ __launch_bounds__(256) void k_blocksum(const int* __restrict__ counts, int N,
                                                  int* __restrict__ bsum) {
    int idx = blockIdx.x * 256 + threadIdx.x;
    int v = (idx < N) ? counts[idx] : 0;
#pragma unroll
    for (int off = 32; off; off >>= 1) v += __shfl_xor(v, off);
    __shared__ int wsum[4];
    if ((threadIdx.x & 63) == 0) wsum[threadIdx.x >> 6] = v;
    __syncthreads();
    if (threadIdx.x == 0) bsum[blockIdx.x] = wsum[0] + wsum[1] + wsum[2] + wsum[3];
}

__global__ __launch_bounds__(256) void k_scanfinal(const int* __restrict__ counts,
                                                   const int* __restrict__ bsum, int N,
                                                   int* __restrict__ rowstart,
                                                   int* __restrict__ cursor) {
    __shared__ int tmp[256];
    __shared__ int wsum[4];
    int t = threadIdx.x, b = blockIdx.x;
    int p = 0;
    for (int i = t; i < b; i += 256) p += bsum[i];
#pragma unroll
    for (int off = 32; off; off >>= 1) p += __shfl_xor(p, off);
    int idx = b * 256 + t;
    int v = (idx < N) ? counts[idx] : 0;
    tmp[t] = v;
    if ((t & 63) == 0) wsum[t >> 6] = p;
    __syncthreads();
    int bp = wsum[0] + wsum[1] + wsum[2] + wsum[3];
    for (int off = 1; off < 256; off <<= 1) {
        int u = (t >= off) ? tmp[t - off] : 0;
        __syncthreads();
        tmp[t] += u;
        __syncthreads();
    }
    if (idx < N) {
        int incl = bp + tmp[t];
        rowstart[idx + 1] = incl;
        cursor[idx] = incl - v;
    }
    if (idx == 0) rowstart[0] = 0;
}

__global__ void k_scatter(const int* __restrict__ src, const int* __restrict__ dst, int E,
                          int* __restrict__ cursor, int* __restrict__ csr_src) {
    int i = blockIdx.x * blockDim.x + threadIdx.x;
    if (i < E) {
        int p = atomicAdd(&cursor[dst[i]], 1);
        csr_src[p] = src[i];
    }
}

// ---------------- fused conversion: x -> f16 plane, W[l] -> transposed f16 ----------------

__device__ inline void wdecomp_body(const float* __restrict__ W, _Float16* __restrict__ Wt,
                                    int K, int bb) {
    int i = bb * 256 + threadIdx.x;
    int k = i >> 8, n = i & 255;
    Wt[n * K + k] = (_Float16)W[i];
}

__global__ __launch_bounds__(256) void k_convert(
    const float* __restrict__ X, _Float16* __restrict__ Xf, int bx,
    const float* __restrict__ W0, _Float16* __restrict__ Wt0,
    const float* __restrict__ W1, _Float16* __restrict__ Wt1,
    const float* __restrict__ W2, _Float16* __restrict__ Wt2) {
    int b = blockIdx.x;
    if (b < bx) {
        int i = b * 256 + threadIdx.x;
        float4 v = ((const float4*)X)[i];
        f16x4 o = {(_Float16)v.x, (_Float16)v.y, (_Float16)v.z, (_Float16)v.w};
        ((f16x4*)Xf)[i] = o;
    } else if (b < bx + 128) {
        wdecomp_body(W0, Wt0, INCH, b - bx);
    } else if (b < bx + 384) {
        wdecomp_body(W1, Wt1, FDIM, b - bx - 128);
    } else {
        wdecomp_body(W2, Wt2, FDIM, b - bx - 384);
    }
}

// ---------------- f16 MFMA GEMM, BM=64, double-buffered gld_lds, fused scores ----------------
// (round-6 measured-good version; only change: scores are pre-scaled by LOG2E so the
// aggregate can use exp2f == v_exp_f32 directly. Scaling commutes with leaky-relu.)

__global__ __launch_bounds__(256) void k_gemm_mfma(
    const _Float16* __restrict__ A, const _Float16* __restrict__ B,
    const float* __restrict__ av, const float* __restrict__ dv,
    _Float16* __restrict__ Hf,
    float* __restrict__ ssrcO, float* __restrict__ sdstO, int M, int K) {
    __shared__ _Float16 sA[2][BM * BK];
    __shared__ _Float16 sB[2][BN * BK];

    const int t = threadIdx.x;
    const int row0 = blockIdx.x * BM;
    const int wv = t >> 6, ln = t & 63, lr = ln & 15, lk = ln >> 4;

    const int ar = wv * 16 + (ln >> 2);
    const int alc = (ln & 3) ^ ((ar >> 1) & 3);
    const size_t agoff = (size_t)min(row0 + ar, M - 1) * K + alc * 8;
    const int fsc = lk ^ ((lr >> 1) & 3);

    f32x4 acc[4][4] = {};
    const int nt = K / BK;

#define STAGE(tt, p)                                                        \
    do {                                                                    \
        int _k0 = (tt)*BK;                                                  \
        gld_lds16(A + agoff + _k0, &sA[p][wv * 512]);                       \
        _Pragma("unroll") for (int _j = 0; _j < 4; ++_j) {                  \
            int _br = _j * 64 + ar;                                         \
            gld_lds16(B + (size_t)_br * K + _k0 + alc * 8,                  \
                      &sB[p][_j * 2048 + wv * 512]);                        \
        }                                                                   \
    } while (0)

    STAGE(0, 0);
    __syncthreads();
    for (int tt = 0; tt < nt; ++tt) {
        int cur = tt & 1;
        if (tt + 1 < nt) STAGE(tt + 1, cur ^ 1);

        f16x8 af[4];
#pragma unroll
        for (int mi = 0; mi < 4; ++mi)
            af[mi] = *(const f16x8*)&sA[cur][(mi * 16 + lr) * BK + fsc * 8];
#pragma unroll
        for (int ni = 0; ni < 4; ++ni) {
            f16x8 bf = *(const f16x8*)&sB[cur][(wv * 64 + ni * 16 + lr) * BK + fsc * 8];
#pragma unroll
            for (int mi = 0; mi < 4; ++mi)
                acc[mi][ni] = __builtin_amdgcn_mfma_f32_16x16x32_f16(af[mi], bf, acc[mi][ni], 0, 0, 0);
        }
        __syncthreads();
    }
#undef STAGE

    float ps[4][4] = {}, pd[4][4] = {};
#pragma unroll
    for (int ni = 0; ni < 4; ++ni) {
        int col = wv * 64 + ni * 16 + lr;
        float a_s = av[col] * LOG2E, a_d = dv[col] * LOG2E;
#pragma unroll
        for (int mi = 0; mi < 4; ++mi) {
            f32x4 v = acc[mi][ni];
            int r = row0 + mi * 16 + lk * 4;
#pragma unroll
            for (int j = 0; j < 4; ++j) {
                if (r + j < M) Hf[(size_t)(r + j) * FDIM + col] = (_Float16)v[j];
                ps[mi][j] += v[j] * a_s;
                pd[mi][j] += v[j] * a_d;
            }
        }
    }
#pragma unroll
    for (int mi = 0; mi < 4; ++mi) {
#pragma unroll
        for (int j = 0; j < 4; ++j) {
            float s = ps[mi][j], q = pd[mi][j];
            s += __shfl_xor(s, 1); s += __shfl_xor(s, 2);
            s += __shfl_xor(s, 4); s += __shfl_xor(s, 8);
            q += __shfl_xor(q, 1); q += __shfl_xor(q, 2);
            q += __shfl_xor(q, 4); q += __shfl_xor(q, 8);
            if (lr == 0) {
                int r = row0 + mi * 16 + lk * 4 + j;
                if (r < M) {
                    ssrcO[r * HEADS + wv] = s;
                    sdstO[r * HEADS + wv] = q;
                }
            }
        }
    }
}

// ---------------- flash softmax + aggregation: R6 structure, exp2f (scores pre-scaled) ----------------

__global__ __launch_bounds__(256) void k_aggregate(
    const _Float16* __restrict__ hf,
    const float* __restrict__ ssrc, const float* __restrict__ sdst,
    const int* __restrict__ rowstart, const int* __restrict__ csr_src,
    const float* __restrict__ bias,
    _Float16* __restrict__ outf, int N) {
    int wv = threadIdx.x >> 6, ln = threadIdx.x & 63;
    int n = blockIdx.x * 4 + wv;
    if (n >= N) return;
    int head = ln >> 4;
    int fo = head * 64 + (ln & 15) * 4;
    float sd = sdst[n * HEADS + head];
    float e = ssrc[n * HEADS + head] + sd;
    e = (e > 0.f) ? e : NEG_SLOPE * e;          // scaled domain: leaky commutes with *LOG2E
    float m = e, d = 1.0f;
    f16x4 sv = *(const f16x4*)&hf[(size_t)n * FDIM + fo];
    float4 acc = make_float4((float)sv[0], (float)sv[1], (float)sv[2], (float)sv[3]);
    int r0 = rowstart[n], r1 = rowstart[n + 1];
    int cnt = r1 - r0;
    for (int base = 0; base < cnt; base += 8) {
        int s[8];
        f16x4 u[8];
        float c[8], w[8];
#pragma unroll
        for (int i = 0; i < 8; ++i) s[i] = csr_src[min(r0 + base + i, r1 - 1)];
#pragma unroll
        for (int i = 0; i < 8; ++i) u[i] = *(const f16x4*)&hf[(size_t)s[i] * FDIM + fo];
#pragma unroll
        for (int i = 0; i < 8; ++i) {
            float sc = ssrc[s[i] * HEADS + head] + sd;
            sc = (sc > 0.f) ? sc : NEG_SLOPE * sc;
            c[i] = (base + i < cnt) ? sc : -1e30f;
        }
        float mx = fmaxf(fmaxf(fmaxf(c[0], c[1]), fmaxf(c[2], c[3])),
                         fmaxf(fmaxf(c[4], c[5]), fmaxf(c[6], c[7])));
        float mn = fmaxf(m, mx);
        float wa = exp2f(m - mn);
#pragma unroll
        for (int i = 0; i < 8; ++i) w[i] = exp2f(c[i] - mn);
        float sx = 0.f, sy = 0.f, sz = 0.f, sw = 0.f, sdn = 0.f;
#pragma unroll
        for (int i = 0; i < 8; ++i) {
            sx += w[i] * (float)u[i][0];
            sy += w[i] * (float)u[i][1];
            sz += w[i] * (float)u[i][2];
            sw += w[i] * (float)u[i][3];
            sdn += w[i];
        }
        acc.x = acc.x * wa + sx;
        acc.y = acc.y * wa + sy;
        acc.z = acc.z * wa + sz;
        acc.w = acc.w * wa + sw;
        d = d * wa + sdn;
        m = mn;
    }
    float inv = 1.0f / d;
    float4 bv = *(const float4*)&bias[fo];
    f16x4 o;
    o[0] = (_Float16)fmaxf(acc.x * inv + bv.x, 0.f);
    o[1] = (_Float16)fmaxf(acc.y * inv + bv.y, 0.f);
    o[2] = (_Float16)fmaxf(acc.z * inv + bv.z, 0.f);
    o[3] = (_Float16)fmaxf(acc.w * inv + bv.w, 0.f);
    *(f16x4*)&outf[(size_t)n * FDIM + fo] = o;
}

// ---------------- pooling (batch sorted, f16 plane) ----------------

__global__ __launch_bounds__(256) void k_pool(const _Float16* __restrict__ hf,
                                              const int* __restrict__ batch,
                                              float* __restrict__ pooled, int N) {
    int f = threadIdx.x;
    int n0 = blockIdx.x * 128;
    if (n0 >= N) return;
    int n1 = min(n0 + 128, N);
    int g = batch[n0];
    float run = 0.f;
    for (int n = n0; n < n1; ++n) {
        int gn = batch[n];
        if (gn != g) {
            atomicAdd(&pooled[g * FDIM + f], run);
            run = 0.f;
            g = gn;
        }
        run += (float)hf[(size_t)n * FDIM + f];
    }
    atomicAdd(&pooled[g * FDIM + f], run);
}

// ---------------- final classifier ----------------

__global__ __launch_bounds__(256) void k_final(const float* __restrict__ pooled,
                                               const float* __restrict__ Wc,
                                               const float* __restrict__ bc,
                                               float* __restrict__ out) {
    int tid = blockIdx.x * 256 + threadIdx.x;
    int g = tid >> 4, o = tid & 15;
    float s = bc[o];
    for (int k = 0; k < FDIM; ++k) s += pooled[g * FDIM + k] * Wc[k * OUTCH + o];
    out[g * OUTCH + o] = s;
}

// ---------------- launch ----------------

extern "C" void kernel_launch(void* const* d_in, const int* in_sizes, int n_in,
                              void* d_out, int out_size, void* d_ws, size_t ws_size,
                              hipStream_t stream) {
    const float* x = (const float*)d_in[0];
    const int* edge_index = (const int*)d_in[2];
    const int* batch = (const int*)d_in[3];
    const float* W[3]    = {(const float*)d_in[4], (const float*)d_in[8],  (const float*)d_in[12]};
    const float* asrc[3] = {(const float*)d_in[5], (const float*)d_in[9],  (const float*)d_in[13]};
    const float* adst[3] = {(const float*)d_in[6], (const float*)d_in[10], (const float*)d_in[14]};
    const float* bias[3] = {(const float*)d_in[7], (const float*)d_in[11], (const float*)d_in[15]};
    const float* Wc = (const float*)d_in[16];
    const float* bc = (const float*)d_in[17];

    const int N = in_sizes[3];
    const int E = in_sizes[2] / 2;
    const int* e_src = edge_index;
    const int* e_dst = edge_index + E;

    char* ws = (char*)d_ws;
    size_t off = 0;
    _Float16* hb = (_Float16*)(ws + off); off += (size_t)N * FDIM * 2;
    _Float16* xf = (_Float16*)(ws + off); off += (size_t)N * INCH * 2;
    _Float16* P  = (_Float16*)(ws + off); off += (size_t)N * FDIM * 2;
    float* ssrc = (float*)(ws + off); off += (size_t)N * HEADS * 4;
    float* sdst = (float*)(ws + off); off += (size_t)N * HEADS * 4;
    int* rowstart = (int*)(ws + off); off += ((size_t)(N + 1) * 4 + 255) / 256 * 256;
    int* counts = (int*)(ws + off); off += (size_t)N * 4;
    int* cursor = (int*)(ws + off); off += (size_t)N * 4;
    int* csr_src = (int*)(ws + off); off += (size_t)E * 4;
    float* pooled = (float*)(ws + off); off += (size_t)NGRAPHS * FDIM * 4;
    int* bsum = (int*)(ws + off); off += ((size_t)((N + 255) / 256) * 4 + 255) / 256 * 256;
    _Float16* Wt[3];
    int Ks[3] = {INCH, FDIM, FDIM};
    for (int l = 0; l < 3; ++l) {
        Wt[l] = (_Float16*)(ws + off); off += (size_t)256 * Ks[l] * 2;
    }

    const int nb = (N + 255) / 256;

    // ---- CSR build ----
    hipMemsetAsync(counts, 0, (size_t)N * 4, stream);
    k_hist<<<(E + 255) / 256, 256, 0, stream>>>(e_dst, E, counts);
    k_blocksum<<<nb, 256, 0, stream>>>(counts, N, bsum);
    k_scanfinal<<<nb, 256, 0, stream>>>(counts, bsum, N, rowstart, cursor);
    k_scatter<<<(E + 255) / 256, 256, 0, stream>>>(e_src, e_dst, E, cursor, csr_src);

    // ---- fused input + weight conversion (1 launch) ----
    {
        int bx = (N * INCH / 4) / 256;
        int btot = bx + (Ks[0] * 256) / 256 + (Ks[1] * 256) / 256 + (Ks[2] * 256) / 256;
        k_convert<<<btot, 256, 0, stream>>>(x, xf, bx, W[0], Wt[0], W[1], Wt[1], W[2], Wt[2]);
    }

    // ---- 3 GAT layers ----
    const _Float16* Af = xf;
    for (int l = 0; l < 3; ++l) {
        int K = Ks[l];
        k_gemm_mfma<<<(N + BM - 1) / BM, 256, 0, stream>>>(Af, Wt[l], asrc[l], adst[l],
                                                           hb, ssrc, sdst, N, K);
        k_aggregate<<<(N + 3) / 4, 256, 0, stream>>>(hb, ssrc, sdst, rowstart, csr_src,
                                                     bias[l], P, N);
        Af = P;
    }

    // ---- pool + classifier ----
    hipMemsetAsync(pooled, 0, (size_t)NGRAPHS * FDIM * 4, stream);
    k_pool<<<(N + 127) / 128, 256, 0, stream>>>(P, batch, pooled, N);
    k_final<<<4, 256, 0, stream>>>(pooled, Wc, bc, (float*)d_out);
}

// Round 12
// 334.944 us; speedup vs baseline: 1.2286x; 1.0359x over previous
//
#include <hip/hip_runtime.h>
#include <hip/hip_bf16.h>

#define NNODES 50000
#define NEDGES 500000
#define INCH 128
#define HID 64
#define HEADS 4
#define FDIM 256
#define NGRAPHS 64
#define OUTCH 16
#define NEG_SLOPE 0.2f
#define LOG2E 1.44269504089f

#define BM 64
#define BN 256
#define BK 32

typedef float f32x4 __attribute__((ext_vector_type(4)));
typedef _Float16 f16x8 __attribute__((ext_vector_type(8)));
typedef _Float16 f16x4 __attribute__((ext_vector_type(4)));

__device__ inline void gld_lds16(const void* g, void* l) {
    __builtin_amdgcn_global_load_lds((__attribute__((address_space(1))) void*)g,
                                     (__attribute__((address_space(3))) void*)l, 16, 0, 0);
}

// ---------------- CSR build ----------------

__global__ void k_hist(const int* __restrict__ dst, int E, int* __restrict__ counts) {
    int i = blockIdx.x * blockDim.x + threadIdx.x;
    if (i < E) atomicAdd(&counts[dst[i]], 1);
}

__global__ __launch_bounds__(256) void k_blocksum(const int* __restrict__ counts, int N,
                                                  int* __restrict__ bsum) {
    int idx = blockIdx.x * 256 + threadIdx.x;
    int v = (idx < N) ? counts[idx] : 0;
#pragma unroll
    for (int off = 32; off; off >>= 1) v += __shfl_xor(v, off);
    __shared__ int wsum[4];
    if ((threadIdx.x & 63) == 0) wsum[threadIdx.x >> 6] = v;
    __syncthreads();
    if (threadIdx.x == 0) bsum[blockIdx.x] = wsum[0] + wsum[1] + wsum[2] + wsum[3];
}

__global__ __launch_bounds__(256) void k_scanfinal(const int* __restrict__ counts,
                                                   const int* __restrict__ bsum, int N,
                                                   int* __restrict__ rowstart,
                                                   int* __restrict__ cursor) {
    __shared__ int tmp[256];
    __shared__ int wsum[4];
    int t = threadIdx.x, b = blockIdx.x;
    int p = 0;
    for (int i = t; i < b; i += 256) p += bsum[i];
#pragma unroll
    for (int off = 32; off; off >>= 1) p += __shfl_xor(p, off);
    int idx = b * 256 + t;
    int v = (idx < N) ? counts[idx] : 0;
    tmp[t] = v;
    if ((t & 63) == 0) wsum[t >> 6] = p;
    __syncthreads();
    int bp = wsum[0] + wsum[1] + wsum[2] + wsum[3];
    for (int off = 1; off < 256; off <<= 1) {
        int u = (t >= off) ? tmp[t - off] : 0;
        __syncthreads();
        tmp[t] += u;
        __syncthreads();
    }
    if (idx < N) {
        int incl = bp + tmp[t];
        rowstart[idx + 1] = incl;
        cursor[idx] = incl - v;
    }
    if (idx == 0) rowstart[0] = 0;
}

__global__ void k_scatter(const int* __restrict__ src, const int* __restrict__ dst, int E,
                          int* __restrict__ cursor, int* __restrict__ csr_src) {
    int i = blockIdx.x * blockDim.x + threadIdx.x;
    if (i < E) {
        int p = atomicAdd(&cursor[dst[i]], 1);
        csr_src[p] = src[i];
    }
}

// ---------------- fused conversion: x -> f16 plane, W[l] -> transposed f16 ----------------

__device__ inline void wdecomp_body(const float* __restrict__ W, _Float16* __restrict__ Wt,
                                    int K, int bb) {
    int i = bb * 256 + threadIdx.x;
    int k = i >> 8, n = i & 255;
    Wt[n * K + k] = (_Float16)W[i];
}

__global__ __launch_bounds__(256) void k_convert(
    const float* __restrict__ X, _Float16* __restrict__ Xf, int bx,
    const float* __restrict__ W0, _Float16* __restrict__ Wt0,
    const float* __restrict__ W1, _Float16* __restrict__ Wt1,
    const float* __restrict__ W2, _Float16* __restrict__ Wt2) {
    int b = blockIdx.x;
    if (b < bx) {
        int i = b * 256 + threadIdx.x;
        float4 v = ((const float4*)X)[i];
        f16x4 o = {(_Float16)v.x, (_Float16)v.y, (_Float16)v.z, (_Float16)v.w};
        ((f16x4*)Xf)[i] = o;
    } else if (b < bx + 128) {
        wdecomp_body(W0, Wt0, INCH, b - bx);
    } else if (b < bx + 384) {
        wdecomp_body(W1, Wt1, FDIM, b - bx - 128);
    } else {
        wdecomp_body(W2, Wt2, FDIM, b - bx - 384);
    }
}

// ---------------- f16 MFMA GEMM, BM=64, double-buffered gld_lds, fused scores ----------------
// (round-6 measured-good version; scores pre-scaled by LOG2E so the aggregate can use the
// raw v_exp_f32 (__builtin_amdgcn_exp2f). Scaling commutes with leaky-relu.)

__global__ __launch_bounds__(256) void k_gemm_mfma(
    const _Float16* __restrict__ A, const _Float16* __restrict__ B,
    const float* __restrict__ av, const float* __restrict__ dv,
    _Float16* __restrict__ Hf,
    float* __restrict__ ssrcO, float* __restrict__ sdstO, int M, int K) {
    __shared__ _Float16 sA[2][BM * BK];
    __shared__ _Float16 sB[2][BN * BK];

    const int t = threadIdx.x;
    const int row0 = blockIdx.x * BM;
    const int wv = t >> 6, ln = t & 63, lr = ln & 15, lk = ln >> 4;

    const int ar = wv * 16 + (ln >> 2);
    const int alc = (ln & 3) ^ ((ar >> 1) & 3);
    const size_t agoff = (size_t)min(row0 + ar, M - 1) * K + alc * 8;
    const int fsc = lk ^ ((lr >> 1) & 3);

    f32x4 acc[4][4] = {};
    const int nt = K / BK;

#define STAGE(tt, p)                                                        \
    do {                                                                    \
        int _k0 = (tt)*BK;                                                  \
        gld_lds16(A + agoff + _k0, &sA[p][wv * 512]);                       \
        _Pragma("unroll") for (int _j = 0; _j < 4; ++_j) {                  \
            int _br = _j * 64 + ar;                                         \
            gld_lds16(B + (size_t)_br * K + _k0 + alc * 8,                  \
                      &sB[p][_j * 2048 + wv * 512]);                        \
        }                                                                   \
    } while (0)

    STAGE(0, 0);
    __syncthreads();
    for (int tt = 0; tt < nt; ++tt) {
        int cur = tt & 1;
        if (tt + 1 < nt) STAGE(tt + 1, cur ^ 1);

        f16x8 af[4];
#pragma unroll
        for (int mi = 0; mi < 4; ++mi)
            af[mi] = *(const f16x8*)&sA[cur][(mi * 16 + lr) * BK + fsc * 8];
#pragma unroll
        for (int ni = 0; ni < 4; ++ni) {
            f16x8 bf = *(const f16x8*)&sB[cur][(wv * 64 + ni * 16 + lr) * BK + fsc * 8];
#pragma unroll
            for (int mi = 0; mi < 4; ++mi)
                acc[mi][ni] = __builtin_amdgcn_mfma_f32_16x16x32_f16(af[mi], bf, acc[mi][ni], 0, 0, 0);
        }
        __syncthreads();
    }
#undef STAGE

    float ps[4][4] = {}, pd[4][4] = {};
#pragma unroll
    for (int ni = 0; ni < 4; ++ni) {
        int col = wv * 64 + ni * 16 + lr;
        float a_s = av[col] * LOG2E, a_d = dv[col] * LOG2E;
#pragma unroll
        for (int mi = 0; mi < 4; ++mi) {
            f32x4 v = acc[mi][ni];
            int r = row0 + mi * 16 + lk * 4;
#pragma unroll
            for (int j = 0; j < 4; ++j) {
                if (r + j < M) Hf[(size_t)(r + j) * FDIM + col] = (_Float16)v[j];
                ps[mi][j] += v[j] * a_s;
                pd[mi][j] += v[j] * a_d;
            }
        }
    }
#pragma unroll
    for (int mi = 0; mi < 4; ++mi) {
#pragma unroll
        for (int j = 0; j < 4; ++j) {
            float s = ps[mi][j], q = pd[mi][j];
            s += __shfl_xor(s, 1); s += __shfl_xor(s, 2);
            s += __shfl_xor(s, 4); s += __shfl_xor(s, 8);
            q += __shfl_xor(q, 1); q += __shfl_xor(q, 2);
            q += __shfl_xor(q, 4); q += __shfl_xor(q, 8);
            if (lr == 0) {
                int r = row0 + mi * 16 + lk * 4 + j;
                if (r < M) {
                    ssrcO[r * HEADS + wv] = s;
                    sdstO[r * HEADS + wv] = q;
                }
            }
        }
    }
}

// ---------------- flash softmax + aggregation: R6 structure, raw v_exp_f32 ----------------

__global__ __launch_bounds__(256) void k_aggregate(
    const _Float16* __restrict__ hf,
    const float* __restrict__ ssrc, const float* __restrict__ sdst,
    const int* __restrict__ rowstart, const int* __restrict__ csr_src,
    const float* __restrict__ bias,
    _Float16* __restrict__ outf, int N) {
    int wv = threadIdx.x >> 6, ln = threadIdx.x & 63;
    int n = blockIdx.x * 4 + wv;
    if (n >= N) return;
    int head = ln >> 4;
    int fo = head * 64 + (ln & 15) * 4;
    float sd = sdst[n * HEADS + head];
    float e = ssrc[n * HEADS + head] + sd;
    e = (e > 0.f) ? e : NEG_SLOPE * e;          // scaled domain: leaky commutes with *LOG2E
    float m = e, d = 1.0f;
    f16x4 sv = *(const f16x4*)&hf[(size_t)n * FDIM + fo];
    float4 acc = make_float4((float)sv[0], (float)sv[1], (float)sv[2], (float)sv[3]);
    int r0 = rowstart[n], r1 = rowstart[n + 1];
    int cnt = r1 - r0;
    for (int base = 0; base < cnt; base += 8) {
        int s[8];
        f16x4 u[8];
        float c[8], w[8];
#pragma unroll
        for (int i = 0; i < 8; ++i) s[i] = csr_src[min(r0 + base + i, r1 - 1)];
#pragma unroll
        for (int i = 0; i < 8; ++i) u[i] = *(const f16x4*)&hf[(size_t)s[i] * FDIM + fo];
#pragma unroll
        for (int i = 0; i < 8; ++i) {
            float sc = ssrc[s[i] * HEADS + head] + sd;
            sc = (sc > 0.f) ? sc : NEG_SLOPE * sc;
            c[i] = (base + i < cnt) ? sc : -1e30f;
        }
        float mx = fmaxf(fmaxf(fmaxf(c[0], c[1]), fmaxf(c[2], c[3])),
                         fmaxf(fmaxf(c[4], c[5]), fmaxf(c[6], c[7])));
        float mn = fmaxf(m, mx);
        float wa = __builtin_amdgcn_exp2f(m - mn);
#pragma unroll
        for (int i = 0; i < 8; ++i) w[i] = __builtin_amdgcn_exp2f(c[i] - mn);
        float sx = 0.f, sy = 0.f, sz = 0.f, sw = 0.f, sdn = 0.f;
#pragma unroll
        for (int i = 0; i < 8; ++i) {
            sx += w[i] * (float)u[i][0];
            sy += w[i] * (float)u[i][1];
            sz += w[i] * (float)u[i][2];
            sw += w[i] * (float)u[i][3];
            sdn += w[i];
        }
        acc.x = acc.x * wa + sx;
        acc.y = acc.y * wa + sy;
        acc.z = acc.z * wa + sz;
        acc.w = acc.w * wa + sw;
        d = d * wa + sdn;
        m = mn;
    }
    float inv = 1.0f / d;
    float4 bv = *(const float4*)&bias[fo];
    f16x4 o;
    o[0] = (_Float16)fmaxf(acc.x * inv + bv.x, 0.f);
    o[1] = (_Float16)fmaxf(acc.y * inv + bv.y, 0.f);
    o[2] = (_Float16)fmaxf(acc.z * inv + bv.z, 0.f);
    o[3] = (_Float16)fmaxf(acc.w * inv + bv.w, 0.f);
    *(f16x4*)&outf[(size_t)n * FDIM + fo] = o;
}

// ---------------- pooling (batch sorted, f16 plane) ----------------

__global__ __launch_bounds__(256) void k_pool(const _Float16* __restrict__ hf,
                                              const int* __restrict__ batch,
                                              float* __restrict__ pooled, int N) {
    int f = threadIdx.x;
    int n0 = blockIdx.x * 128;
    if (n0 >= N) return;
    int n1 = min(n0 + 128, N);
    int g = batch[n0];
    float run = 0.f;
    for (int n = n0; n < n1; ++n) {
        int gn = batch[n];
        if (gn != g) {
            atomicAdd(&pooled[g * FDIM + f], run);
            run = 0.f;
            g = gn;
        }
        run += (float)hf[(size_t)n * FDIM + f];
    }
    atomicAdd(&pooled[g * FDIM + f], run);
}

// ---------------- final classifier ----------------

__global__ __launch_bounds__(256) void k_final(const float* __restrict__ pooled,
                                               const float* __restrict__ Wc,
                                               const float* __restrict__ bc,
                                               float* __restrict__ out) {
    int tid = blockIdx.x * 256 + threadIdx.x;
    int g = tid >> 4, o = tid & 15;
    float s = bc[o];
    for (int k = 0; k < FDIM; ++k) s += pooled[g * FDIM + k] * Wc[k * OUTCH + o];
    out[g * OUTCH + o] = s;
}

// ---------------- launch ----------------

extern "C" void kernel_launch(void* const* d_in, const int* in_sizes, int n_in,
                              void* d_out, int out_size, void* d_ws, size_t ws_size,
                              hipStream_t stream) {
    const float* x = (const float*)d_in[0];
    const int* edge_index = (const int*)d_in[2];
    const int* batch = (const int*)d_in[3];
    const float* W[3]    = {(const float*)d_in[4], (const float*)d_in[8],  (const float*)d_in[12]};
    const float* asrc[3] = {(const float*)d_in[5], (const float*)d_in[9],  (const float*)d_in[13]};
    const float* adst[3] = {(const float*)d_in[6], (const float*)d_in[10], (const float*)d_in[14]};
    const float* bias[3] = {(const float*)d_in[7], (const float*)d_in[11], (const float*)d_in[15]};
    const float* Wc = (const float*)d_in[16];
    const float* bc = (const float*)d_in[17];

    const int N = in_sizes[3];
    const int E = in_sizes[2] / 2;
    const int* e_src = edge_index;
    const int* e_dst = edge_index + E;

    char* ws = (char*)d_ws;
    size_t off = 0;
    _Float16* hb = (_Float16*)(ws + off); off += (size_t)N * FDIM * 2;
    _Float16* xf = (_Float16*)(ws + off); off += (size_t)N * INCH * 2;
    _Float16* P  = (_Float16*)(ws + off); off += (size_t)N * FDIM * 2;
    float* ssrc = (float*)(ws + off); off += (size_t)N * HEADS * 4;
    float* sdst = (float*)(ws + off); off += (size_t)N * HEADS * 4;
    int* rowstart = (int*)(ws + off); off += ((size_t)(N + 1) * 4 + 255) / 256 * 256;
    int* counts = (int*)(ws + off); off += (size_t)N * 4;
    int* cursor = (int*)(ws + off); off += (size_t)N * 4;
    int* csr_src = (int*)(ws + off); off += (size_t)E * 4;
    float* pooled = (float*)(ws + off); off += (size_t)NGRAPHS * FDIM * 4;
    int* bsum = (int*)(ws + off); off += ((size_t)((N + 255) / 256) * 4 + 255) / 256 * 256;
    _Float16* Wt[3];
    int Ks[3] = {INCH, FDIM, FDIM};
    for (int l = 0; l < 3; ++l) {
        Wt[l] = (_Float16*)(ws + off); off += (size_t)256 * Ks[l] * 2;
    }

    const int nb = (N + 255) / 256;

    // ---- CSR build ----
    hipMemsetAsync(counts, 0, (size_t)N * 4, stream);
    k_hist<<<(E + 255) / 256, 256, 0, stream>>>(e_dst, E, counts);
    k_blocksum<<<nb, 256, 0, stream>>>(counts, N, bsum);
    k_scanfinal<<<nb, 256, 0, stream>>>(counts, bsum, N, rowstart, cursor);
    k_scatter<<<(E + 255) / 256, 256, 0, stream>>>(e_src, e_dst, E, cursor, csr_src);

    // ---- fused input + weight conversion (1 launch) ----
    {
        int bx = (N * INCH / 4) / 256;
        int btot = bx + (Ks[0] * 256) / 256 + (Ks[1] * 256) / 256 + (Ks[2] * 256) / 256;
        k_convert<<<btot, 256, 0, stream>>>(x, xf, bx, W[0], Wt[0], W[1], Wt[1], W[2], Wt[2]);
    }

    // ---- 3 GAT layers ----
    const _Float16* Af = xf;
    for (int l = 0; l < 3; ++l) {
        int K = Ks[l];
        k_gemm_mfma<<<(N + BM - 1) / BM, 256, 0, stream>>>(Af, Wt[l], asrc[l], adst[l],
                                                           hb, ssrc, sdst, N, K);
        k_aggregate<<<(N + 3) / 4, 256, 0, stream>>>(hb, ssrc, sdst, rowstart, csr_src,
                                                     bias[l], P, N);
        Af = P;
    }

    // ---- pool + classifier ----
    hipMemsetAsync(pooled, 0, (size_t)NGRAPHS * FDIM * 4, stream);
    k_pool<<<(N + 127) / 128, 256, 0, stream>>>(P, batch, pooled, N);
    k_final<<<4, 256, 0, stream>>>(pooled, Wc, bc, (float*)d_out);
}

// Round 13
// 330.065 us; speedup vs baseline: 1.2467x; 1.0148x over previous
//
#include <hip/hip_runtime.h>
#include <hip/hip_bf16.h>

#define NNODES 50000
#define NEDGES 500000
#define INCH 128
#define HID 64
#define HEADS 4
#define FDIM 256
#define NGRAPHS 64
#define OUTCH 16
#define NEG_SLOPE 0.2f
#define LOG2E 1.44269504089f

#define BM 64
#define BN 256
#define BK 32

typedef float f32x4 __attribute__((ext_vector_type(4)));
typedef _Float16 f16x8 __attribute__((ext_vector_type(8)));
typedef _Float16 f16x4 __attribute__((ext_vector_type(4)));

__device__ inline void gld_lds16(const void* g, void* l) {
    __builtin_amdgcn_global_load_lds((__attribute__((address_space(1))) void*)g,
                                     (__attribute__((address_space(3))) void*)l, 16, 0, 0);
}

// ---------------- CSR build ----------------

__global__ void k_hist(const int* __restrict__ dst, int E, int* __restrict__ counts) {
    int i = blockIdx.x * blockDim.x + threadIdx.x;
    if (i < E) atomicAdd(&counts[dst[i]], 1);
}

__global__ __launch_bounds__(256) void k_blocksum(const int* __restrict__ counts, int N,
                                                  int* __restrict__ bsum) {
    int idx = blockIdx.x * 256 + threadIdx.x;
    int v = (idx < N) ? counts[idx] : 0;
#pragma unroll
    for (int off = 32; off; off >>= 1) v += __shfl_xor(v, off);
    __shared__ int wsum[4];
    if ((threadIdx.x & 63) == 0) wsum[threadIdx.x >> 6] = v;
    __syncthreads();
    if (threadIdx.x == 0) bsum[blockIdx.x] = wsum[0] + wsum[1] + wsum[2] + wsum[3];
}

__global__ __launch_bounds__(256) void k_scanfinal(const int* __restrict__ counts,
                                                   const int* __restrict__ bsum, int N,
                                                   int* __restrict__ rowstart,
                                                   int* __restrict__ cursor) {
    __shared__ int tmp[256];
    __shared__ int wsum[4];
    int t = threadIdx.x, b = blockIdx.x;
    int p = 0;
    for (int i = t; i < b; i += 256) p += bsum[i];
#pragma unroll
    for (int off = 32; off; off >>= 1) p += __shfl_xor(p, off);
    int idx = b * 256 + t;
    int v = (idx < N) ? counts[idx] : 0;
    tmp[t] = v;
    if ((t & 63) == 0) wsum[t >> 6] = p;
    __syncthreads();
    int bp = wsum[0] + wsum[1] + wsum[2] + wsum[3];
    for (int off = 1; off < 256; off <<= 1) {
        int u = (t >= off) ? tmp[t - off] : 0;
        __syncthreads();
        tmp[t] += u;
        __syncthreads();
    }
    if (idx < N) {
        int incl = bp + tmp[t];
        rowstart[idx + 1] = incl;
        cursor[idx] = incl - v;
    }
    if (idx == 0) rowstart[0] = 0;
}

__global__ void k_scatter(const int* __restrict__ src, const int* __restrict__ dst, int E,
                          int* __restrict__ cursor, int* __restrict__ csr_src) {
    int i = blockIdx.x * blockDim.x + threadIdx.x;
    if (i < E) {
        int p = atomicAdd(&cursor[dst[i]], 1);
        csr_src[p] = src[i];
    }
}

// ---------------- fused conversion: x -> f16 plane, W[l] -> transposed f16 ----------------

__device__ inline void wdecomp_body(const float* __restrict__ W, _Float16* __restrict__ Wt,
                                    int K, int bb) {
    int i = bb * 256 + threadIdx.x;
    int k = i >> 8, n = i & 255;
    Wt[n * K + k] = (_Float16)W[i];
}

__global__ __launch_bounds__(256) void k_convert(
    const float* __restrict__ X, _Float16* __restrict__ Xf, int bx,
    const float* __restrict__ W0, _Float16* __restrict__ Wt0,
    const float* __restrict__ W1, _Float16* __restrict__ Wt1,
    const float* __restrict__ W2, _Float16* __restrict__ Wt2) {
    int b = blockIdx.x;
    if (b < bx) {
        int i = b * 256 + threadIdx.x;
        float4 v = ((const float4*)X)[i];
        f16x4 o = {(_Float16)v.x, (_Float16)v.y, (_Float16)v.z, (_Float16)v.w};
        ((f16x4*)Xf)[i] = o;
    } else if (b < bx + 128) {
        wdecomp_body(W0, Wt0, INCH, b - bx);
    } else if (b < bx + 384) {
        wdecomp_body(W1, Wt1, FDIM, b - bx - 128);
    } else {
        wdecomp_body(W2, Wt2, FDIM, b - bx - 384);
    }
}

// ---------------- f16 MFMA GEMM, BM=64, double-buffered gld_lds, fused scores ----------------
// (R12 measured-good version, unchanged: scores pre-scaled by LOG2E)

__global__ __launch_bounds__(256) void k_gemm_mfma(
    const _Float16* __restrict__ A, const _Float16* __restrict__ B,
    const float* __restrict__ av, const float* __restrict__ dv,
    _Float16* __restrict__ Hf,
    float* __restrict__ ssrcO, float* __restrict__ sdstO, int M, int K) {
    __shared__ _Float16 sA[2][BM * BK];
    __shared__ _Float16 sB[2][BN * BK];

    const int t = threadIdx.x;
    const int row0 = blockIdx.x * BM;
    const int wv = t >> 6, ln = t & 63, lr = ln & 15, lk = ln >> 4;

    const int ar = wv * 16 + (ln >> 2);
    const int alc = (ln & 3) ^ ((ar >> 1) & 3);
    const size_t agoff = (size_t)min(row0 + ar, M - 1) * K + alc * 8;
    const int fsc = lk ^ ((lr >> 1) & 3);

    f32x4 acc[4][4] = {};
    const int nt = K / BK;

#define STAGE(tt, p)                                                        \
    do {                                                                    \
        int _k0 = (tt)*BK;                                                  \
        gld_lds16(A + agoff + _k0, &sA[p][wv * 512]);                       \
        _Pragma("unroll") for (int _j = 0; _j < 4; ++_j) {                  \
            int _br = _j * 64 + ar;                                         \
            gld_lds16(B + (size_t)_br * K + _k0 + alc * 8,                  \
                      &sB[p][_j * 2048 + wv * 512]);                        \
        }                                                                   \
    } while (0)

    STAGE(0, 0);
    __syncthreads();
    for (int tt = 0; tt < nt; ++tt) {
        int cur = tt & 1;
        if (tt + 1 < nt) STAGE(tt + 1, cur ^ 1);

        f16x8 af[4];
#pragma unroll
        for (int mi = 0; mi < 4; ++mi)
            af[mi] = *(const f16x8*)&sA[cur][(mi * 16 + lr) * BK + fsc * 8];
#pragma unroll
        for (int ni = 0; ni < 4; ++ni) {
            f16x8 bf = *(const f16x8*)&sB[cur][(wv * 64 + ni * 16 + lr) * BK + fsc * 8];
#pragma unroll
            for (int mi = 0; mi < 4; ++mi)
                acc[mi][ni] = __builtin_amdgcn_mfma_f32_16x16x32_f16(af[mi], bf, acc[mi][ni], 0, 0, 0);
        }
        __syncthreads();
    }
#undef STAGE

    float ps[4][4] = {}, pd[4][4] = {};
#pragma unroll
    for (int ni = 0; ni < 4; ++ni) {
        int col = wv * 64 + ni * 16 + lr;
        float a_s = av[col] * LOG2E, a_d = dv[col] * LOG2E;
#pragma unroll
        for (int mi = 0; mi < 4; ++mi) {
            f32x4 v = acc[mi][ni];
            int r = row0 + mi * 16 + lk * 4;
#pragma unroll
            for (int j = 0; j < 4; ++j) {
                if (r + j < M) Hf[(size_t)(r + j) * FDIM + col] = (_Float16)v[j];
                ps[mi][j] += v[j] * a_s;
                pd[mi][j] += v[j] * a_d;
            }
        }
    }
#pragma unroll
    for (int mi = 0; mi < 4; ++mi) {
#pragma unroll
        for (int j = 0; j < 4; ++j) {
            float s = ps[mi][j], q = pd[mi][j];
            s += __shfl_xor(s, 1); s += __shfl_xor(s, 2);
            s += __shfl_xor(s, 4); s += __shfl_xor(s, 8);
            q += __shfl_xor(q, 1); q += __shfl_xor(q, 2);
            q += __shfl_xor(q, 4); q += __shfl_xor(q, 8);
            if (lr == 0) {
                int r = row0 + mi * 16 + lk * 4 + j;
                if (r < M) {
                    ssrcO[r * HEADS + wv] = s;
                    sdstO[r * HEADS + wv] = q;
                }
            }
        }
    }
}

// ---------------- flash softmax + aggregation: split-wave (even/odd edges), f16x8 lanes ----------------
// Lanes 0-31 accumulate even-indexed edges, lanes 32-63 odd. Each lane covers 8 features
// (16B gathers). The two flash states merge once per node via shfl_xor(32).

__global__ __launch_bounds__(256) void k_aggregate(
    const _Float16* __restrict__ hf,
    const float* __restrict__ ssrc, const float* __restrict__ sdst,
    const int* __restrict__ rowstart, const int* __restrict__ csr_src,
    const float* __restrict__ bias,
    _Float16* __restrict__ outf, int N) {
    int wv = threadIdx.x >> 6, ln = threadIdx.x & 63;
    int n = blockIdx.x * 4 + wv;
    if (n >= N) return;
    int half = ln >> 5;        // 0: even edges (+self), 1: odd edges
    int lh = ln & 31;
    int head = lh >> 3;        // 8 lanes per head
    int fo = lh * 8;           // 8 features per lane
    float sd = sdst[n * HEADS + head];

    float m, d;
    float acc[8];
    {
        f16x8 sv = *(const f16x8*)&hf[(size_t)n * FDIM + fo];
        float e = ssrc[n * HEADS + head] + sd;
        e = (e > 0.f) ? e : NEG_SLOPE * e;
        if (half == 0) {
            m = e; d = 1.0f;
#pragma unroll
            for (int j = 0; j < 8; ++j) acc[j] = (float)sv[j];
        } else {
            m = -1e30f; d = 0.0f;
#pragma unroll
            for (int j = 0; j < 8; ++j) acc[j] = 0.f;
        }
    }
    int r0 = rowstart[n], r1 = rowstart[n + 1];
    int cnt = r1 - r0;
    for (int base = 0; base < cnt; base += 8) {
        int s[4];
        f16x8 u[4];
        float c[4], w[4];
#pragma unroll
        for (int i = 0; i < 4; ++i)
            s[i] = csr_src[min(r0 + base + 2 * i + half, r1 - 1)];
#pragma unroll
        for (int i = 0; i < 4; ++i) u[i] = *(const f16x8*)&hf[(size_t)s[i] * FDIM + fo];
#pragma unroll
        for (int i = 0; i < 4; ++i) {
            float sc = ssrc[s[i] * HEADS + head] + sd;
            sc = (sc > 0.f) ? sc : NEG_SLOPE * sc;
            c[i] = (base + 2 * i + half < cnt) ? sc : -1e30f;
        }
        float mx = fmaxf(fmaxf(c[0], c[1]), fmaxf(c[2], c[3]));
        float mn = fmaxf(m, mx);
        float wa = __builtin_amdgcn_exp2f(m - mn);
#pragma unroll
        for (int i = 0; i < 4; ++i) w[i] = __builtin_amdgcn_exp2f(c[i] - mn);
#pragma unroll
        for (int j = 0; j < 8; ++j) {
            float sj = w[0] * (float)u[0][j] + w[1] * (float)u[1][j] +
                       w[2] * (float)u[2][j] + w[3] * (float)u[3][j];
            acc[j] = acc[j] * wa + sj;
        }
        d = d * wa + ((w[0] + w[1]) + (w[2] + w[3]));
        m = mn;
    }
    // ---- merge the two half-wave flash states (symmetric on both halves) ----
    {
        float pm = __shfl_xor(m, 32);
        float mn = fmaxf(m, pm);
        float wa = __builtin_amdgcn_exp2f(m - mn);   // 0 when m == -1e30
        float wb = __builtin_amdgcn_exp2f(pm - mn);
        float pd = __shfl_xor(d, 32);
        d = d * wa + pd * wb;
#pragma unroll
        for (int j = 0; j < 8; ++j) {
            float pa = __shfl_xor(acc[j], 32);
            acc[j] = acc[j] * wa + pa * wb;
        }
    }
    if (half == 0) {
        float inv = 1.0f / d;
        float4 b0 = *(const float4*)&bias[fo];
        float4 b1 = *(const float4*)&bias[fo + 4];
        f16x8 o;
        o[0] = (_Float16)fmaxf(acc[0] * inv + b0.x, 0.f);
        o[1] = (_Float16)fmaxf(acc[1] * inv + b0.y, 0.f);
        o[2] = (_Float16)fmaxf(acc[2] * inv + b0.z, 0.f);
        o[3] = (_Float16)fmaxf(acc[3] * inv + b0.w, 0.f);
        o[4] = (_Float16)fmaxf(acc[4] * inv + b1.x, 0.f);
        o[5] = (_Float16)fmaxf(acc[5] * inv + b1.y, 0.f);
        o[6] = (_Float16)fmaxf(acc[6] * inv + b1.z, 0.f);
        o[7] = (_Float16)fmaxf(acc[7] * inv + b1.w, 0.f);
        *(f16x8*)&outf[(size_t)n * FDIM + fo] = o;
    }
}

// ---------------- pooling (batch sorted, f16 plane) ----------------

__global__ __launch_bounds__(256) void k_pool(const _Float16* __restrict__ hf,
                                              const int* __restrict__ batch,
                                              float* __restrict__ pooled, int N) {
    int f = threadIdx.x;
    int n0 = blockIdx.x * 128;
    if (n0 >= N) return;
    int n1 = min(n0 + 128, N);
    int g = batch[n0];
    float run = 0.f;
    for (int n = n0; n < n1; ++n) {
        int gn = batch[n];
        if (gn != g) {
            atomicAdd(&pooled[g * FDIM + f], run);
            run = 0.f;
            g = gn;
        }
        run += (float)hf[(size_t)n * FDIM + f];
    }
    atomicAdd(&pooled[g * FDIM + f], run);
}

// ---------------- final classifier ----------------

__global__ __launch_bounds__(256) void k_final(const float* __restrict__ pooled,
                                               const float* __restrict__ Wc,
                                               const float* __restrict__ bc,
                                               float* __restrict__ out) {
    int tid = blockIdx.x * 256 + threadIdx.x;
    int g = tid >> 4, o = tid & 15;
    float s = bc[o];
    for (int k = 0; k < FDIM; ++k) s += pooled[g * FDIM + k] * Wc[k * OUTCH + o];
    out[g * OUTCH + o] = s;
}

// ---------------- launch ----------------

extern "C" void kernel_launch(void* const* d_in, const int* in_sizes, int n_in,
                              void* d_out, int out_size, void* d_ws, size_t ws_size,
                              hipStream_t stream) {
    const float* x = (const float*)d_in[0];
    const int* edge_index = (const int*)d_in[2];
    const int* batch = (const int*)d_in[3];
    const float* W[3]    = {(const float*)d_in[4], (const float*)d_in[8],  (const float*)d_in[12]};
    const float* asrc[3] = {(const float*)d_in[5], (const float*)d_in[9],  (const float*)d_in[13]};
    const float* adst[3] = {(const float*)d_in[6], (const float*)d_in[10], (const float*)d_in[14]};
    const float* bias[3] = {(const float*)d_in[7], (const float*)d_in[11], (const float*)d_in[15]};
    const float* Wc = (const float*)d_in[16];
    const float* bc = (const float*)d_in[17];

    const int N = in_sizes[3];
    const int E = in_sizes[2] / 2;
    const int* e_src = edge_index;
    const int* e_dst = edge_index + E;

    char* ws = (char*)d_ws;
    size_t off = 0;
    _Float16* hb = (_Float16*)(ws + off); off += (size_t)N * FDIM * 2;
    _Float16* xf = (_Float16*)(ws + off); off += (size_t)N * INCH * 2;
    _Float16* P  = (_Float16*)(ws + off); off += (size_t)N * FDIM * 2;
    float* ssrc = (float*)(ws + off); off += (size_t)N * HEADS * 4;
    float* sdst = (float*)(ws + off); off += (size_t)N * HEADS * 4;
    int* rowstart = (int*)(ws + off); off += ((size_t)(N + 1) * 4 + 255) / 256 * 256;
    int* counts = (int*)(ws + off); off += (size_t)N * 4;
    int* cursor = (int*)(ws + off); off += (size_t)N * 4;
    int* csr_src = (int*)(ws + off); off += (size_t)E * 4;
    float* pooled = (float*)(ws + off); off += (size_t)NGRAPHS * FDIM * 4;
    int* bsum = (int*)(ws + off); off += ((size_t)((N + 255) / 256) * 4 + 255) / 256 * 256;
    _Float16* Wt[3];
    int Ks[3] = {INCH, FDIM, FDIM};
    for (int l = 0; l < 3; ++l) {
        Wt[l] = (_Float16*)(ws + off); off += (size_t)256 * Ks[l] * 2;
    }

    const int nb = (N + 255) / 256;

    // ---- CSR build ----
    hipMemsetAsync(counts, 0, (size_t)N * 4, stream);
    k_hist<<<(E + 255) / 256, 256, 0, stream>>>(e_dst, E, counts);
    k_blocksum<<<nb, 256, 0, stream>>>(counts, N, bsum);
    k_scanfinal<<<nb, 256, 0, stream>>>(counts, bsum, N, rowstart, cursor);
    k_scatter<<<(E + 255) / 256, 256, 0, stream>>>(e_src, e_dst, E, cursor, csr_src);

    // ---- fused input + weight conversion (1 launch) ----
    {
        int bx = (N * INCH / 4) / 256;
        int btot = bx + (Ks[0] * 256) / 256 + (Ks[1] * 256) / 256 + (Ks[2] * 256) / 256;
        k_convert<<<btot, 256, 0, stream>>>(x, xf, bx, W[0], Wt[0], W[1], Wt[1], W[2], Wt[2]);
    }

    // ---- 3 GAT layers ----
    const _Float16* Af = xf;
    for (int l = 0; l < 3; ++l) {
        int K = Ks[l];
        k_gemm_mfma<<<(N + BM - 1) / BM, 256, 0, stream>>>(Af, Wt[l], asrc[l], adst[l],
                                                           hb, ssrc, sdst, N, K);
        k_aggregate<<<(N + 3) / 4, 256, 0, stream>>>(hb, ssrc, sdst, rowstart, csr_src,
                                                     bias[l], P, N);
        Af = P;
    }

    // ---- pool + classifier ----
    hipMemsetAsync(pooled, 0, (size_t)NGRAPHS * FDIM * 4, stream);
    k_pool<<<(N + 127) / 128, 256, 0, stream>>>(P, batch, pooled, N);
    k_final<<<4, 256, 0, stream>>>(pooled, Wc, bc, (float*)d_out);
}